// Round 12
// baseline (1151.666 us; speedup 1.0000x reference)
//
#include <hip/hip_runtime.h>

#define NRELS 8
typedef __attribute__((ext_vector_type(8))) short s16x8;
typedef __attribute__((ext_vector_type(4))) float f32x4;
typedef unsigned short u16;
typedef unsigned int u32;

__device__ __forceinline__ u16 f2bf(float v) {
    unsigned u = __float_as_uint(v);
    u += 0x7FFFu + ((u >> 16) & 1u);
    return (u16)(u >> 16);
}
__device__ __forceinline__ float bf2f(u16 h) {
    return __uint_as_float(((unsigned)h) << 16);
}
__device__ __forceinline__ float eluf(float x) { return x > 0.f ? x : __expf(x) - 1.f; }

// ---------------- prep (blocks 0..15) + b0sum (16,17) + hist (18..) ----------------
__global__ void prep_hist(const float* __restrict__ Ws1, const float* __restrict__ Wd1,
                          const float* __restrict__ as1, const float* __restrict__ ad1,
                          const float* __restrict__ b1,
                          const float* __restrict__ Ws2, const float* __restrict__ Wd2,
                          const float* __restrict__ as2, const float* __restrict__ ad2,
                          const float* __restrict__ b2,
                          u16* __restrict__ Wfrag, float* __restrict__ bperm,
                          float* __restrict__ b0sum,
                          const int* __restrict__ edges, int* __restrict__ counts,
                          int E, int N) {
    const int bid = blockIdx.x;
    if (bid >= 18) {
        const int hb = bid - 18;
        const int r = hb & 7;
        const int e = (hb >> 3) * 256 + threadIdx.x;
        if (e >= E) return;
        int d = edges[(size_t)r * 2 * E + E + e];
        atomicAdd(&counts[r * N + d], 1);
        return;
    }
    if (bid >= 16) {
        const int layer = bid - 16;
        const float* bb = layer ? b2 : b1;
        if (threadIdx.x < 128) {
            int p = threadIdx.x;
            int oc = ((p & 7) << 4) | (p >> 3);
            b0sum[layer * 128 + p] = bb[1 * 128 + oc] + bb[3 * 128 + oc]
                                   + bb[5 * 128 + oc] + bb[7 * 128 + oc];
        }
        return;
    }
    const int layer = bid >> 3, r = bid & 7, r1 = r ^ 1;
    const float* Ws  = (layer ? Ws2 : Ws1) + (size_t)r  * 16384;
    const float* asp = (layer ? as2 : as1) + r  * 128;
    const float* Wdr = (layer ? Wd2 : Wd1) + (size_t)r1 * 16384;
    const float* adr = (layer ? ad2 : ad1) + r1 * 128;
    const float* bb  = (layer ? b2  : b1 ) + r  * 128;
    u16* wf = Wfrag + (size_t)bid * 18432;
    for (int f = threadIdx.x; f < 18432; f += blockDim.x) {
        int be   = f & 7;
        int lane = (f >> 3) & 63;
        int kc   = (f >> 9) & 3;
        int ct   = f >> 11;
        int k    = kc * 32 + (lane >> 4) * 8 + be;
        int krow = layer ? (((k & 7) << 4) | (k >> 3)) : k;
        int c    = lane & 15;
        float val;
        if (ct < 8) {
            val = Ws[(size_t)krow * 128 + ct * 16 + c];
        } else if (c < 4) {
            float s = 0.f;
            #pragma unroll
            for (int cc = 0; cc < 32; ++cc) s += Ws[(size_t)krow * 128 + c * 32 + cc] * asp[c * 32 + cc];
            val = s;
        } else if (c < 8) {
            int h = c - 4;
            float s = 0.f;
            #pragma unroll
            for (int cc = 0; cc < 32; ++cc) s += Wdr[(size_t)krow * 128 + h * 32 + cc] * adr[h * 32 + cc];
            val = s;
        } else {
            val = 0.f;
        }
        wf[f] = f2bf(val);
    }
    if (threadIdx.x < 128) {
        int p = threadIdx.x;
        bperm[bid * 128 + p] = bb[((p & 7) << 4) | (p >> 3)];
    }
}

// ---------------- shared gemm inner body ----------------
__device__ __forceinline__ void gemm_phases(const s16x8 af[2][4], u16* wlds,
        const u16* __restrict__ WfragL, int rel0, int nph,
        u16* __restrict__ Hs8, float* __restrict__ es8, float* __restrict__ ed8,
        int r0, int N, int tid) {
    const int l = tid & 63, lr = l & 15, lk = l >> 4;
    for (int ph = 0; ph < nph; ++ph) {
        const int r = rel0 + ph * 2;
        const u16* Wf = WfragL + (size_t)r * 18432;
        __syncthreads();
        for (int i = tid; i < 2304; i += 256)
            ((s16x8*)wlds)[i] = ((const s16x8*)Wf)[i];
        __syncthreads();

        f32x4 acc[2][9] = {};
        #pragma unroll
        for (int ct = 0; ct < 9; ++ct) {
            s16x8 bf0 = ((s16x8*)wlds)[(ct * 4 + 0) * 64 + l];
            s16x8 bf1 = ((s16x8*)wlds)[(ct * 4 + 1) * 64 + l];
            s16x8 bf2 = ((s16x8*)wlds)[(ct * 4 + 2) * 64 + l];
            s16x8 bf3 = ((s16x8*)wlds)[(ct * 4 + 3) * 64 + l];
            #pragma unroll
            for (int rt = 0; rt < 2; ++rt) {
                acc[rt][ct] = __builtin_amdgcn_mfma_f32_16x16x32_bf16(af[rt][0], bf0, acc[rt][ct], 0, 0, 0);
                acc[rt][ct] = __builtin_amdgcn_mfma_f32_16x16x32_bf16(af[rt][1], bf1, acc[rt][ct], 0, 0, 0);
                acc[rt][ct] = __builtin_amdgcn_mfma_f32_16x16x32_bf16(af[rt][2], bf2, acc[rt][ct], 0, 0, 0);
                acc[rt][ct] = __builtin_amdgcn_mfma_f32_16x16x32_bf16(af[rt][3], bf3, acc[rt][ct], 0, 0, 0);
            }
        }

        u16*   Hs = Hs8 + (size_t)r * N * 128;
        float* es = es8 + (size_t)r * N * 4;
        float* ed = ed8 + (size_t)(r ^ 1) * N * 4;
        #pragma unroll
        for (int rt = 0; rt < 2; ++rt) {
            #pragma unroll
            for (int j = 0; j < 4; ++j) {
                int row = r0 + rt * 16 + lk * 4 + j;
                if (row < N) {
                    union { u16 u[8]; uint4 q; } pk;
                    #pragma unroll
                    for (int ct = 0; ct < 8; ++ct) pk.u[ct] = f2bf(acc[rt][ct][j]);
                    *(uint4*)(Hs + (size_t)row * 128 + lr * 8) = pk.q;
                    float evv = acc[rt][8][j];
                    if (lr < 4)      es[(size_t)row * 4 + lr]     = evv;
                    else if (lr < 8) ed[(size_t)row * 4 + lr - 4] = evv;
                }
            }
        }
    }
}

__device__ __forceinline__ void ymap(int y, int& rel0, int& nph, int& stype) {
    if (y < 2) { rel0 = y * 4;           nph = 2; stype = 0; }
    else       { rel0 = 2 * (y - 2) + 1; nph = 1; stype = y - 1; }
}

// ---------------- fused: layer-1 gemm (fp32 in) INTERLEAVED with CSR build ----------
__global__ __launch_bounds__(256) void gemm1_build(
        const float* __restrict__ x0, const float* __restrict__ x1,
        const float* __restrict__ x2, const float* __restrict__ x3,
        const float* __restrict__ x4,
        const u16* __restrict__ WfragL,
        u16* __restrict__ Hs8, float* __restrict__ es8, float* __restrict__ ed8,
        const int* __restrict__ edges, int* __restrict__ pos, int* __restrict__ srcs,
        int gemmBlocks, int E, int N) {
    __shared__ u16 wlds[18432];
    const int bx = blockIdx.x;
    const int q = bx / 3, rm = bx % 3;
    const int tid = threadIdx.x;

    if (rm != 0) {
        const int bi = bx - q - 1;
        const int nEB = (E + 255) / 256;
        if (bi >= 8 * nEB) return;
        const int rel = bi & 7;
        const int e = (bi >> 3) * 256 + tid;
        if (e >= E) return;
        const int* b = edges + (size_t)rel * 2 * E;
        int s = b[e], d = b[E + e];
        int idx = atomicAdd(&pos[rel * N + d], 1);
        srcs[idx] = s;
        return;
    }
    if (q >= gemmBlocks * 6) return;
    const int gx = q % gemmBlocks;
    const int y  = q / gemmBlocks;
    int rel0, nph, stype;
    ymap(y, rel0, nph, stype);

    const int l = tid & 63, lr = l & 15, lk = l >> 4;
    const int wv = tid >> 6;
    const int r0 = gx * 128 + wv * 32;

    const float* Xf = stype == 0 ? x0 : stype == 1 ? x1 : stype == 2 ? x2
                    : stype == 3 ? x3 : x4;
    s16x8 af[2][4];
    #pragma unroll
    for (int rt = 0; rt < 2; ++rt) {
        int row = r0 + rt * 16 + lr;
        if (row > N - 1) row = N - 1;
        const float* xp = Xf + (size_t)row * 128 + lk * 8;
        #pragma unroll
        for (int qq = 0; qq < 4; ++qq) {
            float4 v0 = *(const float4*)(xp + qq * 32);
            float4 v1 = *(const float4*)(xp + qq * 32 + 4);
            s16x8 f;
            f[0] = (short)f2bf(v0.x); f[1] = (short)f2bf(v0.y);
            f[2] = (short)f2bf(v0.z); f[3] = (short)f2bf(v0.w);
            f[4] = (short)f2bf(v1.x); f[5] = (short)f2bf(v1.y);
            f[6] = (short)f2bf(v1.z); f[7] = (short)f2bf(v1.w);
            af[rt][qq] = f;
        }
    }
    gemm_phases(af, wlds, WfragL, rel0, nph, Hs8, es8, ed8, r0, N, tid);
}

// ---------------- layer-2 gemm (bf16 Xbf inputs), grid.y = 6 ----------------
__global__ __launch_bounds__(256) void gemm2_mfma(
        const u16* __restrict__ Xbf, const u16* __restrict__ WfragL,
        u16* __restrict__ Hs8, float* __restrict__ es8, float* __restrict__ ed8, int N) {
    __shared__ u16 wlds[18432];
    const int tid = threadIdx.x;
    int rel0, nph, stype;
    ymap(blockIdx.y, rel0, nph, stype);
    const int l = tid & 63, lr = l & 15, lk = l >> 4;
    const int wv = tid >> 6;
    const int r0 = blockIdx.x * 128 + wv * 32;

    const u16* X = Xbf + (size_t)stype * N * 128;
    s16x8 af[2][4];
    #pragma unroll
    for (int rt = 0; rt < 2; ++rt) {
        int row = r0 + rt * 16 + lr;
        if (row > N - 1) row = N - 1;
        const s16x8* xp = (const s16x8*)(X + (size_t)row * 128 + lk * 8);
        af[rt][0] = xp[0]; af[rt][1] = xp[4]; af[rt][2] = xp[8]; af[rt][3] = xp[12];
    }
    gemm_phases(af, wlds, WfragL, rel0, nph, Hs8, es8, ed8, r0, N, tid);
}

// ---------------- scan chain ----------------
__global__ __launch_bounds__(256) void scan_block_k(const int* __restrict__ in,
                                                    int* __restrict__ outv,
                                                    int* __restrict__ bsum, int M) {
    __shared__ int sh[256];
    int t = threadIdx.x;
    int base = blockIdx.x * 2048 + t * 8;
    int vals[8];
    int tot = 0;
    #pragma unroll
    for (int j = 0; j < 8; ++j) {
        int v = (base + j < M) ? in[base + j] : 0;
        vals[j] = tot; tot += v;
    }
    sh[t] = tot;
    __syncthreads();
    for (int ofs = 1; ofs < 256; ofs <<= 1) {
        int y = 0;
        if (t >= ofs) y = sh[t - ofs];
        __syncthreads();
        if (t >= ofs) sh[t] += y;
        __syncthreads();
    }
    int ex = (t == 0) ? 0 : sh[t - 1];
    #pragma unroll
    for (int j = 0; j < 8; ++j)
        if (base + j < M) outv[base + j] = ex + vals[j];
    if (t == 255) bsum[blockIdx.x] = sh[255];
}

__global__ __launch_bounds__(1024) void scan_tops_k(const int* __restrict__ bsum,
                                                    int* __restrict__ bpref, int nb) {
    __shared__ int sh[1024];
    int t = threadIdx.x;
    int v = (t < nb) ? bsum[t] : 0;
    sh[t] = v;
    __syncthreads();
    for (int ofs = 1; ofs < 1024; ofs <<= 1) {
        int y = 0;
        if (t >= ofs) y = sh[t - ofs];
        __syncthreads();
        if (t >= ofs) sh[t] += y;
        __syncthreads();
    }
    if (t < nb) bpref[t] = sh[t] - v;
}

__global__ void scan_add_k(int* __restrict__ outv, int* __restrict__ pos,
                           const int* __restrict__ bpref, int M) {
    int g = blockIdx.x * blockDim.x + threadIdx.x;
    if (g < M) {
        int v = outv[g] + bpref[g >> 11];
        outv[g] = v;
        pos[g] = v;
    }
}

// ---------------- pnorm ----------------
__global__ __launch_bounds__(256) void pnorm_k(
        const int* __restrict__ srcsG, const int* __restrict__ offs,
        const int* __restrict__ counts, const float* __restrict__ es8,
        const float* __restrict__ ed8, float* __restrict__ pcsr, int N) {
    const int r = blockIdx.y;
    const int* OFF = offs + (size_t)r * N;
    const int* CNT = counts + (size_t)r * N;
    const float* ES = es8 + (size_t)r * N * 4;
    const float* ED = ed8 + (size_t)r * N * 4;
    int g = blockIdx.x * 256 + threadIdx.x;
    if (g >= N * 4) return;
    const int d = g >> 2, h = g & 3;
    const int o0 = OFF[d], dg = CNT[d];
    if (dg == 0) return;
    const float edv = ED[(size_t)d * 4 + h];
    float lc[8];
    float mx = -INFINITY;
    #pragma unroll
    for (int i = 0; i < 8; ++i) {
        if (i < dg) {
            int s = srcsG[o0 + i];
            float lv = ES[(size_t)s * 4 + h] + edv;
            lv = lv > 0.f ? lv : 0.2f * lv;
            lc[i] = lv;
            mx = fmaxf(mx, lv);
        }
    }
    for (int i = 8; i < dg; ++i) {
        int s = srcsG[o0 + i];
        float lv = ES[(size_t)s * 4 + h] + edv;
        lv = lv > 0.f ? lv : 0.2f * lv;
        mx = fmaxf(mx, lv);
    }
    float den = 0.f;
    #pragma unroll
    for (int i = 0; i < 8; ++i) {
        if (i < dg) { lc[i] = __expf(lc[i] - mx); den += lc[i]; }
    }
    for (int i = 8; i < dg; ++i) {
        int s = srcsG[o0 + i];
        float lv = ES[(size_t)s * 4 + h] + edv;
        lv = lv > 0.f ? lv : 0.2f * lv;
        den += __expf(lv - mx);
    }
    const float inv = 1.f / (den + 1e-16f);
    #pragma unroll
    for (int i = 0; i < 8; ++i) {
        if (i < dg) pcsr[(size_t)(o0 + i) * 4 + h] = lc[i] * inv;
    }
    for (int i = 8; i < dg; ++i) {
        int s = srcsG[o0 + i];
        float lv = ES[(size_t)s * 4 + h] + edv;
        lv = lv > 0.f ? lv : 0.2f * lv;
        pcsr[(size_t)(o0 + i) * 4 + h] = __expf(lv - mx) * inv;
    }
}

__device__ __forceinline__ void acc_one(float a[8], float4 p4, uint4 hv) {
    a[0] += p4.x * bf2f((u16)(hv.x & 0xFFFF)); a[1] += p4.x * bf2f((u16)(hv.x >> 16));
    a[2] += p4.y * bf2f((u16)(hv.y & 0xFFFF)); a[3] += p4.y * bf2f((u16)(hv.y >> 16));
    a[4] += p4.z * bf2f((u16)(hv.z & 0xFFFF)); a[5] += p4.z * bf2f((u16)(hv.z >> 16));
    a[6] += p4.w * bf2f((u16)(hv.w & 0xFFFF)); a[7] += p4.w * bf2f((u16)(hv.w >> 16));
}

// tail for dg>4 (rare)
__device__ __noinline__ void acc_tail(float a[8], const int* __restrict__ srcsG,
        const float* __restrict__ pcsr, const u16* __restrict__ HS,
        int o0, int dg, int ln) {
    for (int i = 4; i < dg; ++i) {
        int idx = o0 + i;
        int s = srcsG[idx];
        float4 p4 = *(const float4*)(pcsr + (size_t)idx * 4);
        uint4 hv  = *(const uint4*)(HS + (size_t)s * 128 + 8 * ln);
        acc_one(a, p4, hv);
    }
}

// ---------------- merged gather: y=0 -> dst type 0 (rels 1,3,5,7); y=1..4 -> type y.
// All first-4-edge loads are branchless+clamped so the 4 relations' load chains
// (y=0) overlap in flight. OUT_MODE 0: ELU->bf16 perm (Xbf). 2: ELU fp32 unperm.
template<int OUT_MODE>
__global__ __launch_bounds__(256) void gat_all(
        const int* __restrict__ srcsG, const float* __restrict__ pcsr,
        const int* __restrict__ offs, const int* __restrict__ counts,
        const u16* __restrict__ Hs8, const float* __restrict__ bpermL,
        const float* __restrict__ b0sumL, void* __restrict__ outBase,
        int totE, int N) {
    __shared__ float stg[4][4][132];   // padded: gl*132 % 32 = gl*4 -> no bank aliasing
    const int y   = blockIdx.y;
    const int tid = threadIdx.x;
    const int ln  = tid & 15;
    const int d   = (blockIdx.x * 256 + tid) >> 4;
    const bool act = (d < N);
    const int ds = act ? d : 0;

    float a[8] = {};
    const float* bb;
    size_t slice;
    if (y == 0) {
        int o0v[4], dgv[4];
        #pragma unroll
        for (int rr = 0; rr < 4; ++rr) {
            const int rel = 2 * rr + 1;
            o0v[rr] = offs[(size_t)rel * N + ds];
            dgv[rr] = act ? counts[(size_t)rel * N + ds] : 0;
        }
        // batched branchless loads: all 16 srcs+p4 then all 16 rows in flight
        int   sv[4][4];
        float4 pv[4][4];
        #pragma unroll
        for (int rr = 0; rr < 4; ++rr) {
            #pragma unroll
            for (int i = 0; i < 4; ++i) {
                int idx = o0v[rr] + (i < dgv[rr] ? i : 0);
                idx = min(idx, totE - 1);
                sv[rr][i] = srcsG[idx];
                float4 p4 = *(const float4*)(pcsr + (size_t)idx * 4);
                if (i >= dgv[rr]) { p4.x = 0.f; p4.y = 0.f; p4.z = 0.f; p4.w = 0.f; }
                pv[rr][i] = p4;
            }
        }
        #pragma unroll
        for (int rr = 0; rr < 4; ++rr) {
            const u16* HS = Hs8 + (size_t)(2 * rr + 1) * N * 128;
            #pragma unroll
            for (int i = 0; i < 4; ++i) {
                uint4 hv = *(const uint4*)(HS + (size_t)sv[rr][i] * 128 + 8 * ln);
                acc_one(a, pv[rr][i], hv);
            }
            if (dgv[rr] > 4)
                acc_tail(a, srcsG, pcsr, HS, o0v[rr], dgv[rr], ln);
        }
        bb = b0sumL;
        slice = 0;
    } else {
        const int rel = 2 * (y - 1);
        const u16* HS = Hs8 + (size_t)rel * N * 128;
        const int o0 = offs[(size_t)rel * N + ds];
        const int dg = act ? counts[(size_t)rel * N + ds] : 0;
        #pragma unroll
        for (int i = 0; i < 4; ++i) {
            int idx = o0 + (i < dg ? i : 0);
            idx = min(idx, totE - 1);
            int s = srcsG[idx];
            float4 p4 = *(const float4*)(pcsr + (size_t)idx * 4);
            if (i >= dg) { p4.x = 0.f; p4.y = 0.f; p4.z = 0.f; p4.w = 0.f; }
            uint4 hv = *(const uint4*)(HS + (size_t)s * 128 + 8 * ln);
            acc_one(a, p4, hv);
        }
        if (dg > 4)
            acc_tail(a, srcsG, pcsr, HS, o0, dg, ln);
        bb = bpermL + (size_t)rel * 128;
        slice = (size_t)y * N * 128;
    }

    float4 b0 = *(const float4*)(bb + 8 * ln);
    float4 b1 = *(const float4*)(bb + 8 * ln + 4);
    a[0] += b0.x; a[1] += b0.y; a[2] += b0.z; a[3] += b0.w;
    a[4] += b1.x; a[5] += b1.y; a[6] += b1.z; a[7] += b1.w;

    if (OUT_MODE == 0) {
        if (act) {
            u16* OP = (u16*)outBase + slice;
            union { u16 u[8]; uint4 q; } pk;
            #pragma unroll
            for (int j = 0; j < 8; ++j) pk.u[j] = f2bf(eluf(a[j]));
            *(uint4*)(OP + (size_t)d * 128 + 8 * ln) = pk.q;
        }
    } else {
        const int wv = tid >> 6, gl = (tid >> 4) & 3;
        if (act) {
            #pragma unroll
            for (int j = 0; j < 8; ++j)
                stg[wv][gl][(j << 4) | ln] = eluf(a[j]);
        }
        __syncthreads();
        if (act) {
            float* o = (float*)outBase + slice + (size_t)d * 128;
            *(float4*)(o + 8 * ln)     = *(float4*)&stg[wv][gl][8 * ln];
            *(float4*)(o + 8 * ln + 4) = *(float4*)&stg[wv][gl][8 * ln + 4];
        }
    }
}

extern "C" void kernel_launch(void* const* d_in, const int* in_sizes, int n_in,
                              void* d_out, int out_size, void* d_ws, size_t ws_size,
                              hipStream_t stream) {
    const int N = in_sizes[0] / 128;
    const int E = in_sizes[5] / (2 * NRELS);

    const float* xs0[5] = { (const float*)d_in[0], (const float*)d_in[1],
                            (const float*)d_in[2], (const float*)d_in[3],
                            (const float*)d_in[4] };
    const int*   edges = (const int*)d_in[5];
    const float* Ws1 = (const float*)d_in[6];
    const float* Wd1 = (const float*)d_in[7];
    const float* as1 = (const float*)d_in[8];
    const float* ad1 = (const float*)d_in[9];
    const float* b1  = (const float*)d_in[10];
    const float* Ws2 = (const float*)d_in[11];
    const float* Wd2 = (const float*)d_in[12];
    const float* as2 = (const float*)d_in[13];
    const float* ad2 = (const float*)d_in[14];
    const float* b2  = (const float*)d_in[15];
    float* out = (float*)d_out;

    // workspace layout (~417 MB; ws_size ~1 GB)
    char* wp = (char*)d_ws;
    u16*   Xbf   = (u16*)wp;   wp += (size_t)5 * N * 128 * 2;
    u16*   Hs8   = (u16*)wp;   wp += (size_t)8 * N * 128 * 2;
    float* es8   = (float*)wp; wp += (size_t)8 * N * 4 * 4;
    float* ed8   = (float*)wp; wp += (size_t)8 * N * 4 * 4;
    float* pcsr  = (float*)wp; wp += (size_t)NRELS * E * 4 * 4;
    int* counts  = (int*)wp;   wp += (size_t)NRELS * N * 4;
    int* offs    = (int*)wp;   wp += (size_t)NRELS * N * 4;
    int* pos     = (int*)wp;   wp += (size_t)NRELS * N * 4;
    int* srcs    = (int*)wp;   wp += (size_t)NRELS * E * 4;
    u16* Wfrag   = (u16*)wp;   wp += (size_t)16 * 18432 * 2;
    float* bperm = (float*)wp; wp += (size_t)16 * 128 * 4;
    float* b0sum = (float*)wp; wp += (size_t)2 * 128 * 4;
    int* bsum    = (int*)wp;   wp += 1024 * 4;
    int* bpref   = (int*)wp;   wp += 1024 * 4;
    const size_t ws_used = (size_t)(wp - (char*)d_ws);
    if (ws_used > ws_size) return;

    // ---- zero ONLY the atomic histogram (write-before-read audit holds elsewhere) --
    const int M = NRELS * N;
    hipMemsetAsync(counts, 0, (size_t)M * 4, stream);

    const int nEB = (E + 255) / 256;
    const int eblocks = 8 * nEB;

    prep_hist<<<dim3(18 + eblocks), 256, 0, stream>>>(
        Ws1, Wd1, as1, ad1, b1, Ws2, Wd2, as2, ad2, b2,
        Wfrag, bperm, b0sum, edges, counts, E, N);

    const int nb = (M + 2047) / 2048;
    scan_block_k<<<dim3(nb), 256, 0, stream>>>(counts, offs, bsum, M);
    scan_tops_k<<<dim3(1), 1024, 0, stream>>>(bsum, bpref, nb);
    scan_add_k<<<dim3((M + 255) / 256), 256, 0, stream>>>(offs, pos, bpref, M);

    const int gemmBlocks  = (N + 127) / 128;
    const int G6          = gemmBlocks * 6;
    const int gBlocks     = (N + 15) / 16;
    const int pnormBlocks = (N * 4 + 255) / 256;
    const int totE        = NRELS * E;

    const int K = (G6 > (eblocks + 1) / 2) ? G6 : (eblocks + 1) / 2;

    for (int layer = 0; layer < 2; ++layer) {
        const u16*   WL = Wfrag + (size_t)layer * 8 * 18432;
        const float* bL = bperm + layer * 8 * 128;

        if (layer == 0) {
            gemm1_build<<<dim3(3 * K), 256, 0, stream>>>(
                xs0[0], xs0[1], xs0[2], xs0[3], xs0[4],
                WL, Hs8, es8, ed8, edges, pos, srcs, gemmBlocks, E, N);
        } else {
            gemm2_mfma<<<dim3(gemmBlocks, 6), 256, 0, stream>>>(
                Xbf, WL, Hs8, es8, ed8, N);
        }

        pnorm_k<<<dim3(pnormBlocks, 8), 256, 0, stream>>>(
            srcs, offs, counts, es8, ed8, pcsr, N);

        if (layer == 0)
            gat_all<0><<<dim3(gBlocks, 5), 256, 0, stream>>>(
                srcs, pcsr, offs, counts, Hs8, bL, b0sum + 0 * 128, Xbf, totE, N);
        else
            gat_all<2><<<dim3(gBlocks, 5), 256, 0, stream>>>(
                srcs, pcsr, offs, counts, Hs8, bL, b0sum + 1 * 128, out, totE, N);
    }
}

// Round 13
// 847.132 us; speedup vs baseline: 1.3595x; 1.3595x over previous
//
#include <hip/hip_runtime.h>

#define NRELS 8
typedef __attribute__((ext_vector_type(8))) short s16x8;
typedef __attribute__((ext_vector_type(4))) float f32x4;
typedef unsigned short u16;
typedef unsigned int u32;

__device__ __forceinline__ u16 f2bf(float v) {
    unsigned u = __float_as_uint(v);
    u += 0x7FFFu + ((u >> 16) & 1u);
    return (u16)(u >> 16);
}
__device__ __forceinline__ float bf2f(u16 h) {
    return __uint_as_float(((unsigned)h) << 16);
}
__device__ __forceinline__ float eluf(float x) { return x > 0.f ? x : __expf(x) - 1.f; }

// ---------------- prep (blocks 0..15) + b0sum (16,17) + hist (18..) ----------------
__global__ void prep_hist(const float* __restrict__ Ws1, const float* __restrict__ Wd1,
                          const float* __restrict__ as1, const float* __restrict__ ad1,
                          const float* __restrict__ b1,
                          const float* __restrict__ Ws2, const float* __restrict__ Wd2,
                          const float* __restrict__ as2, const float* __restrict__ ad2,
                          const float* __restrict__ b2,
                          u16* __restrict__ Wfrag, float* __restrict__ bperm,
                          float* __restrict__ b0sum,
                          const int* __restrict__ edges, int* __restrict__ counts,
                          int E, int N) {
    const int bid = blockIdx.x;
    if (bid >= 18) {
        const int hb = bid - 18;
        const int r = hb & 7;
        const int e = (hb >> 3) * 256 + threadIdx.x;
        if (e >= E) return;
        int d = edges[(size_t)r * 2 * E + E + e];
        atomicAdd(&counts[r * N + d], 1);
        return;
    }
    if (bid >= 16) {
        const int layer = bid - 16;
        const float* bb = layer ? b2 : b1;
        if (threadIdx.x < 128) {
            int p = threadIdx.x;
            int oc = ((p & 7) << 4) | (p >> 3);
            b0sum[layer * 128 + p] = bb[1 * 128 + oc] + bb[3 * 128 + oc]
                                   + bb[5 * 128 + oc] + bb[7 * 128 + oc];
        }
        return;
    }
    const int layer = bid >> 3, r = bid & 7, r1 = r ^ 1;
    const float* Ws  = (layer ? Ws2 : Ws1) + (size_t)r  * 16384;
    const float* asp = (layer ? as2 : as1) + r  * 128;
    const float* Wdr = (layer ? Wd2 : Wd1) + (size_t)r1 * 16384;
    const float* adr = (layer ? ad2 : ad1) + r1 * 128;
    const float* bb  = (layer ? b2  : b1 ) + r  * 128;
    u16* wf = Wfrag + (size_t)bid * 18432;
    for (int f = threadIdx.x; f < 18432; f += blockDim.x) {
        int be   = f & 7;
        int lane = (f >> 3) & 63;
        int kc   = (f >> 9) & 3;
        int ct   = f >> 11;
        int k    = kc * 32 + (lane >> 4) * 8 + be;
        int krow = layer ? (((k & 7) << 4) | (k >> 3)) : k;
        int c    = lane & 15;
        float val;
        if (ct < 8) {
            val = Ws[(size_t)krow * 128 + ct * 16 + c];
        } else if (c < 4) {
            float s = 0.f;
            #pragma unroll
            for (int cc = 0; cc < 32; ++cc) s += Ws[(size_t)krow * 128 + c * 32 + cc] * asp[c * 32 + cc];
            val = s;
        } else if (c < 8) {
            int h = c - 4;
            float s = 0.f;
            #pragma unroll
            for (int cc = 0; cc < 32; ++cc) s += Wdr[(size_t)krow * 128 + h * 32 + cc] * adr[h * 32 + cc];
            val = s;
        } else {
            val = 0.f;
        }
        wf[f] = f2bf(val);
    }
    if (threadIdx.x < 128) {
        int p = threadIdx.x;
        bperm[bid * 128 + p] = bb[((p & 7) << 4) | (p >> 3)];
    }
}

// ---------------- shared gemm inner body ----------------
__device__ __forceinline__ void gemm_phases(const s16x8 af[2][4], u16* wlds,
        const u16* __restrict__ WfragL, int rel0, int nph,
        u16* __restrict__ Hs8, float* __restrict__ es8, float* __restrict__ ed8,
        int r0, int N, int tid) {
    const int l = tid & 63, lr = l & 15, lk = l >> 4;
    for (int ph = 0; ph < nph; ++ph) {
        const int r = rel0 + ph * 2;
        const u16* Wf = WfragL + (size_t)r * 18432;
        __syncthreads();
        for (int i = tid; i < 2304; i += 256)
            ((s16x8*)wlds)[i] = ((const s16x8*)Wf)[i];
        __syncthreads();

        f32x4 acc[2][9] = {};
        #pragma unroll
        for (int ct = 0; ct < 9; ++ct) {
            s16x8 bf0 = ((s16x8*)wlds)[(ct * 4 + 0) * 64 + l];
            s16x8 bf1 = ((s16x8*)wlds)[(ct * 4 + 1) * 64 + l];
            s16x8 bf2 = ((s16x8*)wlds)[(ct * 4 + 2) * 64 + l];
            s16x8 bf3 = ((s16x8*)wlds)[(ct * 4 + 3) * 64 + l];
            #pragma unroll
            for (int rt = 0; rt < 2; ++rt) {
                acc[rt][ct] = __builtin_amdgcn_mfma_f32_16x16x32_bf16(af[rt][0], bf0, acc[rt][ct], 0, 0, 0);
                acc[rt][ct] = __builtin_amdgcn_mfma_f32_16x16x32_bf16(af[rt][1], bf1, acc[rt][ct], 0, 0, 0);
                acc[rt][ct] = __builtin_amdgcn_mfma_f32_16x16x32_bf16(af[rt][2], bf2, acc[rt][ct], 0, 0, 0);
                acc[rt][ct] = __builtin_amdgcn_mfma_f32_16x16x32_bf16(af[rt][3], bf3, acc[rt][ct], 0, 0, 0);
            }
        }

        u16*   Hs = Hs8 + (size_t)r * N * 128;
        float* es = es8 + (size_t)r * N * 4;
        float* ed = ed8 + (size_t)(r ^ 1) * N * 4;
        #pragma unroll
        for (int rt = 0; rt < 2; ++rt) {
            #pragma unroll
            for (int j = 0; j < 4; ++j) {
                int row = r0 + rt * 16 + lk * 4 + j;
                if (row < N) {
                    union { u16 u[8]; uint4 q; } pk;
                    #pragma unroll
                    for (int ct = 0; ct < 8; ++ct) pk.u[ct] = f2bf(acc[rt][ct][j]);
                    *(uint4*)(Hs + (size_t)row * 128 + lr * 8) = pk.q;
                    float evv = acc[rt][8][j];
                    if (lr < 4)      es[(size_t)row * 4 + lr]     = evv;
                    else if (lr < 8) ed[(size_t)row * 4 + lr - 4] = evv;
                }
            }
        }
    }
}

__device__ __forceinline__ void ymap(int y, int& rel0, int& nph, int& stype) {
    if (y < 2) { rel0 = y * 4;           nph = 2; stype = 0; }
    else       { rel0 = 2 * (y - 2) + 1; nph = 1; stype = y - 1; }
}

// ---------------- fused: layer-1 gemm (fp32 in) INTERLEAVED with CSR build ----------
__global__ __launch_bounds__(256) void gemm1_build(
        const float* __restrict__ x0, const float* __restrict__ x1,
        const float* __restrict__ x2, const float* __restrict__ x3,
        const float* __restrict__ x4,
        const u16* __restrict__ WfragL,
        u16* __restrict__ Hs8, float* __restrict__ es8, float* __restrict__ ed8,
        const int* __restrict__ edges, int* __restrict__ pos, int* __restrict__ srcs,
        int gemmBlocks, int E, int N) {
    __shared__ u16 wlds[18432];
    const int bx = blockIdx.x;
    const int q = bx / 3, rm = bx % 3;
    const int tid = threadIdx.x;

    if (rm != 0) {
        const int bi = bx - q - 1;
        const int nEB = (E + 255) / 256;
        if (bi >= 8 * nEB) return;
        const int rel = bi & 7;
        const int e = (bi >> 3) * 256 + tid;
        if (e >= E) return;
        const int* b = edges + (size_t)rel * 2 * E;
        int s = b[e], d = b[E + e];
        int idx = atomicAdd(&pos[rel * N + d], 1);
        srcs[idx] = s;
        return;
    }
    if (q >= gemmBlocks * 6) return;
    const int gx = q % gemmBlocks;
    const int y  = q / gemmBlocks;
    int rel0, nph, stype;
    ymap(y, rel0, nph, stype);

    const int l = tid & 63, lr = l & 15, lk = l >> 4;
    const int wv = tid >> 6;
    const int r0 = gx * 128 + wv * 32;

    const float* Xf = stype == 0 ? x0 : stype == 1 ? x1 : stype == 2 ? x2
                    : stype == 3 ? x3 : x4;
    s16x8 af[2][4];
    #pragma unroll
    for (int rt = 0; rt < 2; ++rt) {
        int row = r0 + rt * 16 + lr;
        if (row > N - 1) row = N - 1;
        const float* xp = Xf + (size_t)row * 128 + lk * 8;
        #pragma unroll
        for (int qq = 0; qq < 4; ++qq) {
            float4 v0 = *(const float4*)(xp + qq * 32);
            float4 v1 = *(const float4*)(xp + qq * 32 + 4);
            s16x8 f;
            f[0] = (short)f2bf(v0.x); f[1] = (short)f2bf(v0.y);
            f[2] = (short)f2bf(v0.z); f[3] = (short)f2bf(v0.w);
            f[4] = (short)f2bf(v1.x); f[5] = (short)f2bf(v1.y);
            f[6] = (short)f2bf(v1.z); f[7] = (short)f2bf(v1.w);
            af[rt][qq] = f;
        }
    }
    gemm_phases(af, wlds, WfragL, rel0, nph, Hs8, es8, ed8, r0, N, tid);
}

// ---------------- layer-2 gemm (bf16 Xbf inputs), grid.y = 6 ----------------
__global__ __launch_bounds__(256) void gemm2_mfma(
        const u16* __restrict__ Xbf, const u16* __restrict__ WfragL,
        u16* __restrict__ Hs8, float* __restrict__ es8, float* __restrict__ ed8, int N) {
    __shared__ u16 wlds[18432];
    const int tid = threadIdx.x;
    int rel0, nph, stype;
    ymap(blockIdx.y, rel0, nph, stype);
    const int l = tid & 63, lr = l & 15, lk = l >> 4;
    const int wv = tid >> 6;
    const int r0 = blockIdx.x * 128 + wv * 32;

    const u16* X = Xbf + (size_t)stype * N * 128;
    s16x8 af[2][4];
    #pragma unroll
    for (int rt = 0; rt < 2; ++rt) {
        int row = r0 + rt * 16 + lr;
        if (row > N - 1) row = N - 1;
        const s16x8* xp = (const s16x8*)(X + (size_t)row * 128 + lk * 8);
        af[rt][0] = xp[0]; af[rt][1] = xp[4]; af[rt][2] = xp[8]; af[rt][3] = xp[12];
    }
    gemm_phases(af, wlds, WfragL, rel0, nph, Hs8, es8, ed8, r0, N, tid);
}

// ---------------- scan chain ----------------
__global__ __launch_bounds__(256) void scan_block_k(const int* __restrict__ in,
                                                    int* __restrict__ outv,
                                                    int* __restrict__ bsum, int M) {
    __shared__ int sh[256];
    int t = threadIdx.x;
    int base = blockIdx.x * 2048 + t * 8;
    int vals[8];
    int tot = 0;
    #pragma unroll
    for (int j = 0; j < 8; ++j) {
        int v = (base + j < M) ? in[base + j] : 0;
        vals[j] = tot; tot += v;
    }
    sh[t] = tot;
    __syncthreads();
    for (int ofs = 1; ofs < 256; ofs <<= 1) {
        int y = 0;
        if (t >= ofs) y = sh[t - ofs];
        __syncthreads();
        if (t >= ofs) sh[t] += y;
        __syncthreads();
    }
    int ex = (t == 0) ? 0 : sh[t - 1];
    #pragma unroll
    for (int j = 0; j < 8; ++j)
        if (base + j < M) outv[base + j] = ex + vals[j];
    if (t == 255) bsum[blockIdx.x] = sh[255];
}

__global__ __launch_bounds__(1024) void scan_tops_k(const int* __restrict__ bsum,
                                                    int* __restrict__ bpref, int nb) {
    __shared__ int sh[1024];
    int t = threadIdx.x;
    int v = (t < nb) ? bsum[t] : 0;
    sh[t] = v;
    __syncthreads();
    for (int ofs = 1; ofs < 1024; ofs <<= 1) {
        int y = 0;
        if (t >= ofs) y = sh[t - ofs];
        __syncthreads();
        if (t >= ofs) sh[t] += y;
        __syncthreads();
    }
    if (t < nb) bpref[t] = sh[t] - v;
}

__global__ void scan_add_k(int* __restrict__ outv, int* __restrict__ pos,
                           const int* __restrict__ bpref, int M) {
    int g = blockIdx.x * blockDim.x + threadIdx.x;
    if (g < M) {
        int v = outv[g] + bpref[g >> 11];
        outv[g] = v;
        pos[g] = v;
    }
}

// ---------------- pnorm ----------------
__global__ __launch_bounds__(256) void pnorm_k(
        const int* __restrict__ srcsG, const int* __restrict__ offs,
        const int* __restrict__ counts, const float* __restrict__ es8,
        const float* __restrict__ ed8, float* __restrict__ pcsr, int N) {
    const int r = blockIdx.y;
    const int* OFF = offs + (size_t)r * N;
    const int* CNT = counts + (size_t)r * N;
    const float* ES = es8 + (size_t)r * N * 4;
    const float* ED = ed8 + (size_t)r * N * 4;
    int g = blockIdx.x * 256 + threadIdx.x;
    if (g >= N * 4) return;
    const int d = g >> 2, h = g & 3;
    const int o0 = OFF[d], dg = CNT[d];
    if (dg == 0) return;
    const float edv = ED[(size_t)d * 4 + h];
    float lc[8];
    float mx = -INFINITY;
    #pragma unroll
    for (int i = 0; i < 8; ++i) {
        if (i < dg) {
            int s = srcsG[o0 + i];
            float lv = ES[(size_t)s * 4 + h] + edv;
            lv = lv > 0.f ? lv : 0.2f * lv;
            lc[i] = lv;
            mx = fmaxf(mx, lv);
        }
    }
    for (int i = 8; i < dg; ++i) {
        int s = srcsG[o0 + i];
        float lv = ES[(size_t)s * 4 + h] + edv;
        lv = lv > 0.f ? lv : 0.2f * lv;
        mx = fmaxf(mx, lv);
    }
    float den = 0.f;
    #pragma unroll
    for (int i = 0; i < 8; ++i) {
        if (i < dg) { lc[i] = __expf(lc[i] - mx); den += lc[i]; }
    }
    for (int i = 8; i < dg; ++i) {
        int s = srcsG[o0 + i];
        float lv = ES[(size_t)s * 4 + h] + edv;
        lv = lv > 0.f ? lv : 0.2f * lv;
        den += __expf(lv - mx);
    }
    const float inv = 1.f / (den + 1e-16f);
    #pragma unroll
    for (int i = 0; i < 8; ++i) {
        if (i < dg) pcsr[(size_t)(o0 + i) * 4 + h] = lc[i] * inv;
    }
    for (int i = 8; i < dg; ++i) {
        int s = srcsG[o0 + i];
        float lv = ES[(size_t)s * 4 + h] + edv;
        lv = lv > 0.f ? lv : 0.2f * lv;
        pcsr[(size_t)(o0 + i) * 4 + h] = __expf(lv - mx) * inv;
    }
}

// ---------------- gather accumulate for one relation (round-10 form) ----------------
__device__ __forceinline__ void acc_rel(float a[8], const int* __restrict__ srcsG,
        const float* __restrict__ pcsr, const int* __restrict__ OFF,
        const int* __restrict__ CNT, const u16* __restrict__ HS,
        int ds, bool act, int ln) {
    const int o0 = OFF[ds];
    const int dg = act ? CNT[ds] : 0;
    if (dg == 0) return;
    #pragma unroll
    for (int i = 0; i < 4; ++i) {
        int idx = o0 + (i < dg ? i : dg - 1);
        int s = srcsG[idx];
        float4 p4 = *(const float4*)(pcsr + (size_t)idx * 4);
        uint4 hv  = *(const uint4*)(HS + (size_t)s * 128 + 8 * ln);
        if (i >= dg) { p4.x = 0.f; p4.y = 0.f; p4.z = 0.f; p4.w = 0.f; }
        a[0] += p4.x * bf2f((u16)(hv.x & 0xFFFF)); a[1] += p4.x * bf2f((u16)(hv.x >> 16));
        a[2] += p4.y * bf2f((u16)(hv.y & 0xFFFF)); a[3] += p4.y * bf2f((u16)(hv.y >> 16));
        a[4] += p4.z * bf2f((u16)(hv.z & 0xFFFF)); a[5] += p4.z * bf2f((u16)(hv.z >> 16));
        a[6] += p4.w * bf2f((u16)(hv.w & 0xFFFF)); a[7] += p4.w * bf2f((u16)(hv.w >> 16));
    }
    #pragma unroll
    for (int i = 4; i < 8; ++i) {
        if (i < dg) {
            int idx = o0 + i;
            int s = srcsG[idx];
            float4 p4 = *(const float4*)(pcsr + (size_t)idx * 4);
            uint4 hv  = *(const uint4*)(HS + (size_t)s * 128 + 8 * ln);
            a[0] += p4.x * bf2f((u16)(hv.x & 0xFFFF)); a[1] += p4.x * bf2f((u16)(hv.x >> 16));
            a[2] += p4.y * bf2f((u16)(hv.y & 0xFFFF)); a[3] += p4.y * bf2f((u16)(hv.y >> 16));
            a[4] += p4.z * bf2f((u16)(hv.z & 0xFFFF)); a[5] += p4.z * bf2f((u16)(hv.z >> 16));
            a[6] += p4.w * bf2f((u16)(hv.w & 0xFFFF)); a[7] += p4.w * bf2f((u16)(hv.w >> 16));
        }
    }
    for (int i = 8; i < dg; ++i) {
        int idx = o0 + i;
        int s = srcsG[idx];
        float4 p4 = *(const float4*)(pcsr + (size_t)idx * 4);
        uint4 hv  = *(const uint4*)(HS + (size_t)s * 128 + 8 * ln);
        a[0] += p4.x * bf2f((u16)(hv.x & 0xFFFF)); a[1] += p4.x * bf2f((u16)(hv.x >> 16));
        a[2] += p4.y * bf2f((u16)(hv.y & 0xFFFF)); a[3] += p4.y * bf2f((u16)(hv.y >> 16));
        a[4] += p4.z * bf2f((u16)(hv.z & 0xFFFF)); a[5] += p4.z * bf2f((u16)(hv.z >> 16));
        a[6] += p4.w * bf2f((u16)(hv.w & 0xFFFF)); a[7] += p4.w * bf2f((u16)(hv.w >> 16));
    }
}

// ---------------- merged gather (round-10 form): y=0 -> type 0; y=1..4 -> type y ----
// OUT_MODE 0: ELU->bf16 perm layout (Xbf). OUT_MODE 2: ELU fp32 un-permuted (d_out).
template<int OUT_MODE>
__global__ __launch_bounds__(256) void gat_all(
        const int* __restrict__ srcsG, const float* __restrict__ pcsr,
        const int* __restrict__ offs, const int* __restrict__ counts,
        const u16* __restrict__ Hs8, const float* __restrict__ bpermL,
        const float* __restrict__ b0sumL, void* __restrict__ outBase, int N) {
    const int y   = blockIdx.y;
    const int tid = threadIdx.x;
    const int ln  = tid & 15;
    const int d   = (blockIdx.x * 256 + tid) >> 4;
    const bool act = (d < N);
    const int ds = act ? d : 0;

    float a[8] = {};
    const float* bb;
    size_t slice;
    if (y == 0) {
        #pragma unroll
        for (int rr = 0; rr < 4; ++rr) {
            const int rel = 2 * rr + 1;
            acc_rel(a, srcsG, pcsr, offs + (size_t)rel * N, counts + (size_t)rel * N,
                    Hs8 + (size_t)rel * N * 128, ds, act, ln);
        }
        bb = b0sumL;
        slice = 0;
    } else {
        const int rel = 2 * (y - 1);
        acc_rel(a, srcsG, pcsr, offs + (size_t)rel * N, counts + (size_t)rel * N,
                Hs8 + (size_t)rel * N * 128, ds, act, ln);
        bb = bpermL + (size_t)rel * 128;
        slice = (size_t)y * N * 128;
    }
    if (!act) return;

    float4 b0 = *(const float4*)(bb + 8 * ln);
    float4 b1 = *(const float4*)(bb + 8 * ln + 4);
    a[0] += b0.x; a[1] += b0.y; a[2] += b0.z; a[3] += b0.w;
    a[4] += b1.x; a[5] += b1.y; a[6] += b1.z; a[7] += b1.w;

    if (OUT_MODE == 0) {
        u16* OP = (u16*)outBase + slice;
        union { u16 u[8]; uint4 q; } pk;
        #pragma unroll
        for (int j = 0; j < 8; ++j) pk.u[j] = f2bf(eluf(a[j]));
        *(uint4*)(OP + (size_t)d * 128 + 8 * ln) = pk.q;
    } else {
        float* OP = (float*)outBase + slice;
        float* o = OP + (size_t)d * 128;
        #pragma unroll
        for (int j = 0; j < 8; ++j)
            o[(j << 4) | ln] = eluf(a[j]);
    }
}

extern "C" void kernel_launch(void* const* d_in, const int* in_sizes, int n_in,
                              void* d_out, int out_size, void* d_ws, size_t ws_size,
                              hipStream_t stream) {
    const int N = in_sizes[0] / 128;
    const int E = in_sizes[5] / (2 * NRELS);

    const float* xs0[5] = { (const float*)d_in[0], (const float*)d_in[1],
                            (const float*)d_in[2], (const float*)d_in[3],
                            (const float*)d_in[4] };
    const int*   edges = (const int*)d_in[5];
    const float* Ws1 = (const float*)d_in[6];
    const float* Wd1 = (const float*)d_in[7];
    const float* as1 = (const float*)d_in[8];
    const float* ad1 = (const float*)d_in[9];
    const float* b1  = (const float*)d_in[10];
    const float* Ws2 = (const float*)d_in[11];
    const float* Wd2 = (const float*)d_in[12];
    const float* as2 = (const float*)d_in[13];
    const float* ad2 = (const float*)d_in[14];
    const float* b2  = (const float*)d_in[15];
    float* out = (float*)d_out;

    // workspace layout (~417 MB; ws_size ~1 GB)
    char* wp = (char*)d_ws;
    u16*   Xbf   = (u16*)wp;   wp += (size_t)5 * N * 128 * 2;
    u16*   Hs8   = (u16*)wp;   wp += (size_t)8 * N * 128 * 2;
    float* es8   = (float*)wp; wp += (size_t)8 * N * 4 * 4;
    float* ed8   = (float*)wp; wp += (size_t)8 * N * 4 * 4;
    float* pcsr  = (float*)wp; wp += (size_t)NRELS * E * 4 * 4;
    int* counts  = (int*)wp;   wp += (size_t)NRELS * N * 4;
    int* offs    = (int*)wp;   wp += (size_t)NRELS * N * 4;
    int* pos     = (int*)wp;   wp += (size_t)NRELS * N * 4;
    int* srcs    = (int*)wp;   wp += (size_t)NRELS * E * 4;
    u16* Wfrag   = (u16*)wp;   wp += (size_t)16 * 18432 * 2;
    float* bperm = (float*)wp; wp += (size_t)16 * 128 * 4;
    float* b0sum = (float*)wp; wp += (size_t)2 * 128 * 4;
    int* bsum    = (int*)wp;   wp += 1024 * 4;
    int* bpref   = (int*)wp;   wp += 1024 * 4;
    const size_t ws_used = (size_t)(wp - (char*)d_ws);
    if (ws_used > ws_size) return;

    // ---- zero ONLY the atomic histogram (write-before-read audit holds elsewhere) --
    const int M = NRELS * N;
    hipMemsetAsync(counts, 0, (size_t)M * 4, stream);

    const int nEB = (E + 255) / 256;
    const int eblocks = 8 * nEB;

    prep_hist<<<dim3(18 + eblocks), 256, 0, stream>>>(
        Ws1, Wd1, as1, ad1, b1, Ws2, Wd2, as2, ad2, b2,
        Wfrag, bperm, b0sum, edges, counts, E, N);

    const int nb = (M + 2047) / 2048;
    scan_block_k<<<dim3(nb), 256, 0, stream>>>(counts, offs, bsum, M);
    scan_tops_k<<<dim3(1), 1024, 0, stream>>>(bsum, bpref, nb);
    scan_add_k<<<dim3((M + 255) / 256), 256, 0, stream>>>(offs, pos, bpref, M);

    const int gemmBlocks  = (N + 127) / 128;
    const int G6          = gemmBlocks * 6;
    const int gBlocks     = (N + 15) / 16;
    const int pnormBlocks = (N * 4 + 255) / 256;

    const int K = (G6 > (eblocks + 1) / 2) ? G6 : (eblocks + 1) / 2;

    for (int layer = 0; layer < 2; ++layer) {
        const u16*   WL = Wfrag + (size_t)layer * 8 * 18432;
        const float* bL = bperm + layer * 8 * 128;

        if (layer == 0) {
            gemm1_build<<<dim3(3 * K), 256, 0, stream>>>(
                xs0[0], xs0[1], xs0[2], xs0[3], xs0[4],
                WL, Hs8, es8, ed8, edges, pos, srcs, gemmBlocks, E, N);
        } else {
            gemm2_mfma<<<dim3(gemmBlocks, 6), 256, 0, stream>>>(
                Xbf, WL, Hs8, es8, ed8, N);
        }

        pnorm_k<<<dim3(pnormBlocks, 8), 256, 0, stream>>>(
            srcs, offs, counts, es8, ed8, pcsr, N);

        if (layer == 0)
            gat_all<0><<<dim3(gBlocks, 5), 256, 0, stream>>>(
                srcs, pcsr, offs, counts, Hs8, bL, b0sum + 0 * 128, Xbf, N);
        else
            gat_all<2><<<dim3(gBlocks, 5), 256, 0, stream>>>(
                srcs, pcsr, offs, counts, Hs8, bL, b0sum + 1 * 128, out, N);
    }
}

// Round 14
// 837.294 us; speedup vs baseline: 1.3755x; 1.0118x over previous
//
#include <hip/hip_runtime.h>

#define NRELS 8
typedef __attribute__((ext_vector_type(8))) short s16x8;
typedef __attribute__((ext_vector_type(4))) float f32x4;
typedef unsigned short u16;
typedef unsigned int u32;

__device__ __forceinline__ u16 f2bf(float v) {
    unsigned u = __float_as_uint(v);
    u += 0x7FFFu + ((u >> 16) & 1u);
    return (u16)(u >> 16);
}
__device__ __forceinline__ float bf2f(u16 h) {
    return __uint_as_float(((unsigned)h) << 16);
}
__device__ __forceinline__ float eluf(float x) { return x > 0.f ? x : __expf(x) - 1.f; }

// ---------------- prep (blocks 0..15) + b0sum (16,17) + hist (18..) ----------------
__global__ void prep_hist(const float* __restrict__ Ws1, const float* __restrict__ Wd1,
                          const float* __restrict__ as1, const float* __restrict__ ad1,
                          const float* __restrict__ b1,
                          const float* __restrict__ Ws2, const float* __restrict__ Wd2,
                          const float* __restrict__ as2, const float* __restrict__ ad2,
                          const float* __restrict__ b2,
                          u16* __restrict__ Wfrag, float* __restrict__ bperm,
                          float* __restrict__ b0sum,
                          const int* __restrict__ edges, int* __restrict__ counts,
                          int E, int N) {
    const int bid = blockIdx.x;
    if (bid >= 18) {
        const int hb = bid - 18;
        const int r = hb & 7;
        const int e = (hb >> 3) * 256 + threadIdx.x;
        if (e >= E) return;
        int d = edges[(size_t)r * 2 * E + E + e];
        atomicAdd(&counts[r * N + d], 1);
        return;
    }
    if (bid >= 16) {
        const int layer = bid - 16;
        const float* bb = layer ? b2 : b1;
        if (threadIdx.x < 128) {
            int p = threadIdx.x;
            int oc = ((p & 7) << 4) | (p >> 3);
            b0sum[layer * 128 + p] = bb[1 * 128 + oc] + bb[3 * 128 + oc]
                                   + bb[5 * 128 + oc] + bb[7 * 128 + oc];
        }
        return;
    }
    const int layer = bid >> 3, r = bid & 7, r1 = r ^ 1;
    const float* Ws  = (layer ? Ws2 : Ws1) + (size_t)r  * 16384;
    const float* asp = (layer ? as2 : as1) + r  * 128;
    const float* Wdr = (layer ? Wd2 : Wd1) + (size_t)r1 * 16384;
    const float* adr = (layer ? ad2 : ad1) + r1 * 128;
    const float* bb  = (layer ? b2  : b1 ) + r  * 128;
    u16* wf = Wfrag + (size_t)bid * 18432;
    for (int f = threadIdx.x; f < 18432; f += blockDim.x) {
        int be   = f & 7;
        int lane = (f >> 3) & 63;
        int kc   = (f >> 9) & 3;
        int ct   = f >> 11;
        int k    = kc * 32 + (lane >> 4) * 8 + be;
        int krow = layer ? (((k & 7) << 4) | (k >> 3)) : k;
        int c    = lane & 15;
        float val;
        if (ct < 8) {
            val = Ws[(size_t)krow * 128 + ct * 16 + c];
        } else if (c < 4) {
            float s = 0.f;
            #pragma unroll
            for (int cc = 0; cc < 32; ++cc) s += Ws[(size_t)krow * 128 + c * 32 + cc] * asp[c * 32 + cc];
            val = s;
        } else if (c < 8) {
            int h = c - 4;
            float s = 0.f;
            #pragma unroll
            for (int cc = 0; cc < 32; ++cc) s += Wdr[(size_t)krow * 128 + h * 32 + cc] * adr[h * 32 + cc];
            val = s;
        } else {
            val = 0.f;
        }
        wf[f] = f2bf(val);
    }
    if (threadIdx.x < 128) {
        int p = threadIdx.x;
        bperm[bid * 128 + p] = bb[((p & 7) << 4) | (p >> 3)];
    }
}

// ---------------- shared gemm inner body ----------------
__device__ __forceinline__ void gemm_phases(const s16x8 af[2][4], u16* wlds,
        const u16* __restrict__ WfragL, int rel0, int nph,
        u16* __restrict__ Hs8, float* __restrict__ es8, float* __restrict__ ed8,
        int r0, int N, int tid) {
    const int l = tid & 63, lr = l & 15, lk = l >> 4;
    for (int ph = 0; ph < nph; ++ph) {
        const int r = rel0 + ph * 2;
        const u16* Wf = WfragL + (size_t)r * 18432;
        __syncthreads();
        for (int i = tid; i < 2304; i += 256)
            ((s16x8*)wlds)[i] = ((const s16x8*)Wf)[i];
        __syncthreads();

        f32x4 acc[2][9] = {};
        #pragma unroll
        for (int ct = 0; ct < 9; ++ct) {
            s16x8 bf0 = ((s16x8*)wlds)[(ct * 4 + 0) * 64 + l];
            s16x8 bf1 = ((s16x8*)wlds)[(ct * 4 + 1) * 64 + l];
            s16x8 bf2 = ((s16x8*)wlds)[(ct * 4 + 2) * 64 + l];
            s16x8 bf3 = ((s16x8*)wlds)[(ct * 4 + 3) * 64 + l];
            #pragma unroll
            for (int rt = 0; rt < 2; ++rt) {
                acc[rt][ct] = __builtin_amdgcn_mfma_f32_16x16x32_bf16(af[rt][0], bf0, acc[rt][ct], 0, 0, 0);
                acc[rt][ct] = __builtin_amdgcn_mfma_f32_16x16x32_bf16(af[rt][1], bf1, acc[rt][ct], 0, 0, 0);
                acc[rt][ct] = __builtin_amdgcn_mfma_f32_16x16x32_bf16(af[rt][2], bf2, acc[rt][ct], 0, 0, 0);
                acc[rt][ct] = __builtin_amdgcn_mfma_f32_16x16x32_bf16(af[rt][3], bf3, acc[rt][ct], 0, 0, 0);
            }
        }

        u16*   Hs = Hs8 + (size_t)r * N * 128;
        float* es = es8 + (size_t)r * N * 4;
        float* ed = ed8 + (size_t)(r ^ 1) * N * 4;
        #pragma unroll
        for (int rt = 0; rt < 2; ++rt) {
            #pragma unroll
            for (int j = 0; j < 4; ++j) {
                int row = r0 + rt * 16 + lk * 4 + j;
                if (row < N) {
                    union { u16 u[8]; uint4 q; } pk;
                    #pragma unroll
                    for (int ct = 0; ct < 8; ++ct) pk.u[ct] = f2bf(acc[rt][ct][j]);
                    *(uint4*)(Hs + (size_t)row * 128 + lr * 8) = pk.q;
                    float evv = acc[rt][8][j];
                    if (lr < 4)      es[(size_t)row * 4 + lr]     = evv;
                    else if (lr < 8) ed[(size_t)row * 4 + lr - 4] = evv;
                }
            }
        }
    }
}

__device__ __forceinline__ void ymap(int y, int& rel0, int& nph, int& stype) {
    if (y < 2) { rel0 = y * 4;           nph = 2; stype = 0; }
    else       { rel0 = 2 * (y - 2) + 1; nph = 1; stype = y - 1; }
}

// ---------------- fused: layer-1 gemm (fp32 in) INTERLEAVED with CSR build ----------
__global__ __launch_bounds__(256) void gemm1_build(
        const float* __restrict__ x0, const float* __restrict__ x1,
        const float* __restrict__ x2, const float* __restrict__ x3,
        const float* __restrict__ x4,
        const u16* __restrict__ WfragL,
        u16* __restrict__ Hs8, float* __restrict__ es8, float* __restrict__ ed8,
        const int* __restrict__ edges, int* __restrict__ pos, int* __restrict__ srcs,
        int gemmBlocks, int E, int N) {
    __shared__ u16 wlds[18432];
    const int bx = blockIdx.x;
    const int q = bx / 3, rm = bx % 3;
    const int tid = threadIdx.x;

    if (rm != 0) {
        const int bi = bx - q - 1;
        const int nEB = (E + 255) / 256;
        if (bi >= 8 * nEB) return;
        const int rel = bi & 7;
        const int e = (bi >> 3) * 256 + tid;
        if (e >= E) return;
        const int* b = edges + (size_t)rel * 2 * E;
        int s = b[e], d = b[E + e];
        int idx = atomicAdd(&pos[rel * N + d], 1);
        srcs[idx] = s;
        return;
    }
    if (q >= gemmBlocks * 6) return;
    const int gx = q % gemmBlocks;
    const int y  = q / gemmBlocks;
    int rel0, nph, stype;
    ymap(y, rel0, nph, stype);

    const int l = tid & 63, lr = l & 15, lk = l >> 4;
    const int wv = tid >> 6;
    const int r0 = gx * 128 + wv * 32;

    const float* Xf = stype == 0 ? x0 : stype == 1 ? x1 : stype == 2 ? x2
                    : stype == 3 ? x3 : x4;
    s16x8 af[2][4];
    #pragma unroll
    for (int rt = 0; rt < 2; ++rt) {
        int row = r0 + rt * 16 + lr;
        if (row > N - 1) row = N - 1;
        const float* xp = Xf + (size_t)row * 128 + lk * 8;
        #pragma unroll
        for (int qq = 0; qq < 4; ++qq) {
            float4 v0 = *(const float4*)(xp + qq * 32);
            float4 v1 = *(const float4*)(xp + qq * 32 + 4);
            s16x8 f;
            f[0] = (short)f2bf(v0.x); f[1] = (short)f2bf(v0.y);
            f[2] = (short)f2bf(v0.z); f[3] = (short)f2bf(v0.w);
            f[4] = (short)f2bf(v1.x); f[5] = (short)f2bf(v1.y);
            f[6] = (short)f2bf(v1.z); f[7] = (short)f2bf(v1.w);
            af[rt][qq] = f;
        }
    }
    gemm_phases(af, wlds, WfragL, rel0, nph, Hs8, es8, ed8, r0, N, tid);
}

// ---------------- layer-2 gemm (bf16 Xbf inputs), grid.y = 6 ----------------
__global__ __launch_bounds__(256) void gemm2_mfma(
        const u16* __restrict__ Xbf, const u16* __restrict__ WfragL,
        u16* __restrict__ Hs8, float* __restrict__ es8, float* __restrict__ ed8, int N) {
    __shared__ u16 wlds[18432];
    const int tid = threadIdx.x;
    int rel0, nph, stype;
    ymap(blockIdx.y, rel0, nph, stype);
    const int l = tid & 63, lr = l & 15, lk = l >> 4;
    const int wv = tid >> 6;
    const int r0 = blockIdx.x * 128 + wv * 32;

    const u16* X = Xbf + (size_t)stype * N * 128;
    s16x8 af[2][4];
    #pragma unroll
    for (int rt = 0; rt < 2; ++rt) {
        int row = r0 + rt * 16 + lr;
        if (row > N - 1) row = N - 1;
        const s16x8* xp = (const s16x8*)(X + (size_t)row * 128 + lk * 8);
        af[rt][0] = xp[0]; af[rt][1] = xp[4]; af[rt][2] = xp[8]; af[rt][3] = xp[12];
    }
    gemm_phases(af, wlds, WfragL, rel0, nph, Hs8, es8, ed8, r0, N, tid);
}

// ---------------- scan chain ----------------
__global__ __launch_bounds__(256) void scan_block_k(const int* __restrict__ in,
                                                    int* __restrict__ outv,
                                                    int* __restrict__ bsum, int M) {
    __shared__ int sh[256];
    int t = threadIdx.x;
    int base = blockIdx.x * 2048 + t * 8;
    int vals[8];
    int tot = 0;
    #pragma unroll
    for (int j = 0; j < 8; ++j) {
        int v = (base + j < M) ? in[base + j] : 0;
        vals[j] = tot; tot += v;
    }
    sh[t] = tot;
    __syncthreads();
    for (int ofs = 1; ofs < 256; ofs <<= 1) {
        int y = 0;
        if (t >= ofs) y = sh[t - ofs];
        __syncthreads();
        if (t >= ofs) sh[t] += y;
        __syncthreads();
    }
    int ex = (t == 0) ? 0 : sh[t - 1];
    #pragma unroll
    for (int j = 0; j < 8; ++j)
        if (base + j < M) outv[base + j] = ex + vals[j];
    if (t == 255) bsum[blockIdx.x] = sh[255];
}

__global__ __launch_bounds__(1024) void scan_tops_k(const int* __restrict__ bsum,
                                                    int* __restrict__ bpref, int nb) {
    __shared__ int sh[1024];
    int t = threadIdx.x;
    int v = (t < nb) ? bsum[t] : 0;
    sh[t] = v;
    __syncthreads();
    for (int ofs = 1; ofs < 1024; ofs <<= 1) {
        int y = 0;
        if (t >= ofs) y = sh[t - ofs];
        __syncthreads();
        if (t >= ofs) sh[t] += y;
        __syncthreads();
    }
    if (t < nb) bpref[t] = sh[t] - v;
}

__global__ void scan_add_k(int* __restrict__ outv, int* __restrict__ pos,
                           const int* __restrict__ bpref, int M) {
    int g = blockIdx.x * blockDim.x + threadIdx.x;
    if (g < M) {
        int v = outv[g] + bpref[g >> 11];
        outv[g] = v;
        pos[g] = v;
    }
}

// ---------------- pnorm (branchless first-4 for load ILP) ----------------
__global__ __launch_bounds__(256) void pnorm_k(
        const int* __restrict__ srcsG, const int* __restrict__ offs,
        const int* __restrict__ counts, const float* __restrict__ es8,
        const float* __restrict__ ed8, float* __restrict__ pcsr, int N) {
    const int r = blockIdx.y;
    const int* OFF = offs + (size_t)r * N;
    const int* CNT = counts + (size_t)r * N;
    const float* ES = es8 + (size_t)r * N * 4;
    const float* ED = ed8 + (size_t)r * N * 4;
    int g = blockIdx.x * 256 + threadIdx.x;
    if (g >= N * 4) return;
    const int d = g >> 2, h = g & 3;
    const int o0 = OFF[d], dg = CNT[d];
    if (dg == 0) return;
    const float edv = ED[(size_t)d * 4 + h];
    float lc[8];
    float mx = -INFINITY;
    // branchless first 4: clamped index (valid since dg>=1), -INF for masked slots
    #pragma unroll
    for (int i = 0; i < 4; ++i) {
        int idx = o0 + (i < dg ? i : 0);
        int s = srcsG[idx];
        float lv = ES[(size_t)s * 4 + h] + edv;
        lv = lv > 0.f ? lv : 0.2f * lv;
        if (i >= dg) lv = -INFINITY;
        lc[i] = lv;
        mx = fmaxf(mx, lv);
    }
    #pragma unroll
    for (int i = 4; i < 8; ++i) {
        float lv = -INFINITY;
        if (i < dg) {
            int s = srcsG[o0 + i];
            lv = ES[(size_t)s * 4 + h] + edv;
            lv = lv > 0.f ? lv : 0.2f * lv;
            mx = fmaxf(mx, lv);
        }
        lc[i] = lv;
    }
    for (int i = 8; i < dg; ++i) {
        int s = srcsG[o0 + i];
        float lv = ES[(size_t)s * 4 + h] + edv;
        lv = lv > 0.f ? lv : 0.2f * lv;
        mx = fmaxf(mx, lv);
    }
    float den = 0.f;
    #pragma unroll
    for (int i = 0; i < 8; ++i) {
        lc[i] = __expf(lc[i] - mx);   // exp(-INF - mx) = 0 for masked slots
        den += lc[i];
    }
    for (int i = 8; i < dg; ++i) {
        int s = srcsG[o0 + i];
        float lv = ES[(size_t)s * 4 + h] + edv;
        lv = lv > 0.f ? lv : 0.2f * lv;
        den += __expf(lv - mx);
    }
    const float inv = 1.f / (den + 1e-16f);
    #pragma unroll
    for (int i = 0; i < 8; ++i) {
        if (i < dg) pcsr[(size_t)(o0 + i) * 4 + h] = lc[i] * inv;
    }
    for (int i = 8; i < dg; ++i) {
        int s = srcsG[o0 + i];
        float lv = ES[(size_t)s * 4 + h] + edv;
        lv = lv > 0.f ? lv : 0.2f * lv;
        pcsr[(size_t)(o0 + i) * 4 + h] = __expf(lv - mx) * inv;
    }
}

// ---------------- gather accumulate for one relation (o0/dg passed in) ----------------
__device__ __forceinline__ void acc_rel(float a[8], const int* __restrict__ srcsG,
        const float* __restrict__ pcsr, const u16* __restrict__ HS,
        int o0, int dg, int ln) {
    if (dg == 0) return;
    #pragma unroll
    for (int i = 0; i < 4; ++i) {
        int idx = o0 + (i < dg ? i : dg - 1);
        int s = srcsG[idx];
        float4 p4 = *(const float4*)(pcsr + (size_t)idx * 4);
        uint4 hv  = *(const uint4*)(HS + (size_t)s * 128 + 8 * ln);
        if (i >= dg) { p4.x = 0.f; p4.y = 0.f; p4.z = 0.f; p4.w = 0.f; }
        a[0] += p4.x * bf2f((u16)(hv.x & 0xFFFF)); a[1] += p4.x * bf2f((u16)(hv.x >> 16));
        a[2] += p4.y * bf2f((u16)(hv.y & 0xFFFF)); a[3] += p4.y * bf2f((u16)(hv.y >> 16));
        a[4] += p4.z * bf2f((u16)(hv.z & 0xFFFF)); a[5] += p4.z * bf2f((u16)(hv.z >> 16));
        a[6] += p4.w * bf2f((u16)(hv.w & 0xFFFF)); a[7] += p4.w * bf2f((u16)(hv.w >> 16));
    }
    #pragma unroll
    for (int i = 4; i < 8; ++i) {
        if (i < dg) {
            int idx = o0 + i;
            int s = srcsG[idx];
            float4 p4 = *(const float4*)(pcsr + (size_t)idx * 4);
            uint4 hv  = *(const uint4*)(HS + (size_t)s * 128 + 8 * ln);
            a[0] += p4.x * bf2f((u16)(hv.x & 0xFFFF)); a[1] += p4.x * bf2f((u16)(hv.x >> 16));
            a[2] += p4.y * bf2f((u16)(hv.y & 0xFFFF)); a[3] += p4.y * bf2f((u16)(hv.y >> 16));
            a[4] += p4.z * bf2f((u16)(hv.z & 0xFFFF)); a[5] += p4.z * bf2f((u16)(hv.z >> 16));
            a[6] += p4.w * bf2f((u16)(hv.w & 0xFFFF)); a[7] += p4.w * bf2f((u16)(hv.w >> 16));
        }
    }
    for (int i = 8; i < dg; ++i) {
        int idx = o0 + i;
        int s = srcsG[idx];
        float4 p4 = *(const float4*)(pcsr + (size_t)idx * 4);
        uint4 hv  = *(const uint4*)(HS + (size_t)s * 128 + 8 * ln);
        a[0] += p4.x * bf2f((u16)(hv.x & 0xFFFF)); a[1] += p4.x * bf2f((u16)(hv.x >> 16));
        a[2] += p4.y * bf2f((u16)(hv.y & 0xFFFF)); a[3] += p4.y * bf2f((u16)(hv.y >> 16));
        a[4] += p4.z * bf2f((u16)(hv.z & 0xFFFF)); a[5] += p4.z * bf2f((u16)(hv.z >> 16));
        a[6] += p4.w * bf2f((u16)(hv.w & 0xFFFF)); a[7] += p4.w * bf2f((u16)(hv.w >> 16));
    }
}

// ---------------- merged gather: y=0 -> type 0 (rels 1,3,5,7, o0/dg hoisted);
//                  y=1..4 -> type y (rel 2(y-1)).
// OUT_MODE 0: ELU->bf16 perm layout (Xbf). OUT_MODE 2: ELU fp32 un-permuted (d_out).
template<int OUT_MODE>
__global__ __launch_bounds__(256) void gat_all(
        const int* __restrict__ srcsG, const float* __restrict__ pcsr,
        const int* __restrict__ offs, const int* __restrict__ counts,
        const u16* __restrict__ Hs8, const float* __restrict__ bpermL,
        const float* __restrict__ b0sumL, void* __restrict__ outBase, int N) {
    const int y   = blockIdx.y;
    const int tid = threadIdx.x;
    const int ln  = tid & 15;
    const int d   = (blockIdx.x * 256 + tid) >> 4;
    const bool act = (d < N);
    const int ds = act ? d : 0;

    float a[8] = {};
    const float* bb;
    size_t slice;
    if (y == 0) {
        // hoisted metadata: 8 independent loads in flight before any body
        int o0v[4], dgv[4];
        #pragma unroll
        for (int rr = 0; rr < 4; ++rr) {
            const int rel = 2 * rr + 1;
            o0v[rr] = offs[(size_t)rel * N + ds];
            dgv[rr] = act ? counts[(size_t)rel * N + ds] : 0;
        }
        #pragma unroll
        for (int rr = 0; rr < 4; ++rr) {
            acc_rel(a, srcsG, pcsr, Hs8 + (size_t)(2 * rr + 1) * N * 128,
                    o0v[rr], dgv[rr], ln);
        }
        bb = b0sumL;
        slice = 0;
    } else {
        const int rel = 2 * (y - 1);
        const int o0 = offs[(size_t)rel * N + ds];
        const int dg = act ? counts[(size_t)rel * N + ds] : 0;
        acc_rel(a, srcsG, pcsr, Hs8 + (size_t)rel * N * 128, o0, dg, ln);
        bb = bpermL + (size_t)rel * 128;
        slice = (size_t)y * N * 128;
    }
    if (!act) return;

    float4 b0 = *(const float4*)(bb + 8 * ln);
    float4 b1 = *(const float4*)(bb + 8 * ln + 4);
    a[0] += b0.x; a[1] += b0.y; a[2] += b0.z; a[3] += b0.w;
    a[4] += b1.x; a[5] += b1.y; a[6] += b1.z; a[7] += b1.w;

    if (OUT_MODE == 0) {
        u16* OP = (u16*)outBase + slice;
        union { u16 u[8]; uint4 q; } pk;
        #pragma unroll
        for (int j = 0; j < 8; ++j) pk.u[j] = f2bf(eluf(a[j]));
        *(uint4*)(OP + (size_t)d * 128 + 8 * ln) = pk.q;
    } else {
        float* OP = (float*)outBase + slice;
        float* o = OP + (size_t)d * 128;
        #pragma unroll
        for (int j = 0; j < 8; ++j)
            o[(j << 4) | ln] = eluf(a[j]);
    }
}

extern "C" void kernel_launch(void* const* d_in, const int* in_sizes, int n_in,
                              void* d_out, int out_size, void* d_ws, size_t ws_size,
                              hipStream_t stream) {
    const int N = in_sizes[0] / 128;
    const int E = in_sizes[5] / (2 * NRELS);

    const float* xs0[5] = { (const float*)d_in[0], (const float*)d_in[1],
                            (const float*)d_in[2], (const float*)d_in[3],
                            (const float*)d_in[4] };
    const int*   edges = (const int*)d_in[5];
    const float* Ws1 = (const float*)d_in[6];
    const float* Wd1 = (const float*)d_in[7];
    const float* as1 = (const float*)d_in[8];
    const float* ad1 = (const float*)d_in[9];
    const float* b1  = (const float*)d_in[10];
    const float* Ws2 = (const float*)d_in[11];
    const float* Wd2 = (const float*)d_in[12];
    const float* as2 = (const float*)d_in[13];
    const float* ad2 = (const float*)d_in[14];
    const float* b2  = (const float*)d_in[15];
    float* out = (float*)d_out;

    // workspace layout (~417 MB; ws_size ~1 GB)
    char* wp = (char*)d_ws;
    u16*   Xbf   = (u16*)wp;   wp += (size_t)5 * N * 128 * 2;
    u16*   Hs8   = (u16*)wp;   wp += (size_t)8 * N * 128 * 2;
    float* es8   = (float*)wp; wp += (size_t)8 * N * 4 * 4;
    float* ed8   = (float*)wp; wp += (size_t)8 * N * 4 * 4;
    float* pcsr  = (float*)wp; wp += (size_t)NRELS * E * 4 * 4;
    int* counts  = (int*)wp;   wp += (size_t)NRELS * N * 4;
    int* offs    = (int*)wp;   wp += (size_t)NRELS * N * 4;
    int* pos     = (int*)wp;   wp += (size_t)NRELS * N * 4;
    int* srcs    = (int*)wp;   wp += (size_t)NRELS * E * 4;
    u16* Wfrag   = (u16*)wp;   wp += (size_t)16 * 18432 * 2;
    float* bperm = (float*)wp; wp += (size_t)16 * 128 * 4;
    float* b0sum = (float*)wp; wp += (size_t)2 * 128 * 4;
    int* bsum    = (int*)wp;   wp += 1024 * 4;
    int* bpref   = (int*)wp;   wp += 1024 * 4;
    const size_t ws_used = (size_t)(wp - (char*)d_ws);
    if (ws_used > ws_size) return;

    // ---- zero ONLY the atomic histogram (write-before-read audit holds elsewhere) --
    const int M = NRELS * N;
    hipMemsetAsync(counts, 0, (size_t)M * 4, stream);

    const int nEB = (E + 255) / 256;
    const int eblocks = 8 * nEB;

    prep_hist<<<dim3(18 + eblocks), 256, 0, stream>>>(
        Ws1, Wd1, as1, ad1, b1, Ws2, Wd2, as2, ad2, b2,
        Wfrag, bperm, b0sum, edges, counts, E, N);

    const int nb = (M + 2047) / 2048;
    scan_block_k<<<dim3(nb), 256, 0, stream>>>(counts, offs, bsum, M);
    scan_tops_k<<<dim3(1), 1024, 0, stream>>>(bsum, bpref, nb);
    scan_add_k<<<dim3((M + 255) / 256), 256, 0, stream>>>(offs, pos, bpref, M);

    const int gemmBlocks  = (N + 127) / 128;
    const int G6          = gemmBlocks * 6;
    const int gBlocks     = (N + 15) / 16;
    const int pnormBlocks = (N * 4 + 255) / 256;

    const int K = (G6 > (eblocks + 1) / 2) ? G6 : (eblocks + 1) / 2;

    for (int layer = 0; layer < 2; ++layer) {
        const u16*   WL = Wfrag + (size_t)layer * 8 * 18432;
        const float* bL = bperm + layer * 8 * 128;

        if (layer == 0) {
            gemm1_build<<<dim3(3 * K), 256, 0, stream>>>(
                xs0[0], xs0[1], xs0[2], xs0[3], xs0[4],
                WL, Hs8, es8, ed8, edges, pos, srcs, gemmBlocks, E, N);
        } else {
            gemm2_mfma<<<dim3(gemmBlocks, 6), 256, 0, stream>>>(
                Xbf, WL, Hs8, es8, ed8, N);
        }

        pnorm_k<<<dim3(pnormBlocks, 8), 256, 0, stream>>>(
            srcs, offs, counts, es8, ed8, pcsr, N);

        if (layer == 0)
            gat_all<0><<<dim3(gBlocks, 5), 256, 0, stream>>>(
                srcs, pcsr, offs, counts, Hs8, bL, b0sum + 0 * 128, Xbf, N);
        else
            gat_all<2><<<dim3(gBlocks, 5), 256, 0, stream>>>(
                srcs, pcsr, offs, counts, Hs8, bL, b0sum + 1 * 128, out, N);
    }
}

// Round 15
// 830.127 us; speedup vs baseline: 1.3873x; 1.0086x over previous
//
#include <hip/hip_runtime.h>

#define NRELS 8
typedef __attribute__((ext_vector_type(8))) short s16x8;
typedef __attribute__((ext_vector_type(4))) float f32x4;
typedef unsigned short u16;
typedef unsigned int u32;

__device__ __forceinline__ u16 f2bf(float v) {
    unsigned u = __float_as_uint(v);
    u += 0x7FFFu + ((u >> 16) & 1u);
    return (u16)(u >> 16);
}
__device__ __forceinline__ float bf2f(u16 h) {
    return __uint_as_float(((unsigned)h) << 16);
}
__device__ __forceinline__ float eluf(float x) { return x > 0.f ? x : __expf(x) - 1.f; }

// ---------------- prep (blocks 0..15) + b0sum (16,17) + hist (18..) ----------------
__global__ void prep_hist(const float* __restrict__ Ws1, const float* __restrict__ Wd1,
                          const float* __restrict__ as1, const float* __restrict__ ad1,
                          const float* __restrict__ b1,
                          const float* __restrict__ Ws2, const float* __restrict__ Wd2,
                          const float* __restrict__ as2, const float* __restrict__ ad2,
                          const float* __restrict__ b2,
                          u16* __restrict__ Wfrag, float* __restrict__ bperm,
                          float* __restrict__ b0sum,
                          const int* __restrict__ edges, int* __restrict__ counts,
                          int E, int N) {
    const int bid = blockIdx.x;
    if (bid >= 18) {
        const int hb = bid - 18;
        const int r = hb & 7;
        const int e = (hb >> 3) * 256 + threadIdx.x;
        if (e >= E) return;
        int d = edges[(size_t)r * 2 * E + E + e];
        atomicAdd(&counts[r * N + d], 1);
        return;
    }
    if (bid >= 16) {
        const int layer = bid - 16;
        const float* bb = layer ? b2 : b1;
        if (threadIdx.x < 128) {
            int p = threadIdx.x;
            int oc = ((p & 7) << 4) | (p >> 3);
            b0sum[layer * 128 + p] = bb[1 * 128 + oc] + bb[3 * 128 + oc]
                                   + bb[5 * 128 + oc] + bb[7 * 128 + oc];
        }
        return;
    }
    const int layer = bid >> 3, r = bid & 7, r1 = r ^ 1;
    const float* Ws  = (layer ? Ws2 : Ws1) + (size_t)r  * 16384;
    const float* asp = (layer ? as2 : as1) + r  * 128;
    const float* Wdr = (layer ? Wd2 : Wd1) + (size_t)r1 * 16384;
    const float* adr = (layer ? ad2 : ad1) + r1 * 128;
    const float* bb  = (layer ? b2  : b1 ) + r  * 128;
    u16* wf = Wfrag + (size_t)bid * 18432;
    for (int f = threadIdx.x; f < 18432; f += blockDim.x) {
        int be   = f & 7;
        int lane = (f >> 3) & 63;
        int kc   = (f >> 9) & 3;
        int ct   = f >> 11;
        int k    = kc * 32 + (lane >> 4) * 8 + be;
        int krow = layer ? (((k & 7) << 4) | (k >> 3)) : k;
        int c    = lane & 15;
        float val;
        if (ct < 8) {
            val = Ws[(size_t)krow * 128 + ct * 16 + c];
        } else if (c < 4) {
            float s = 0.f;
            #pragma unroll
            for (int cc = 0; cc < 32; ++cc) s += Ws[(size_t)krow * 128 + c * 32 + cc] * asp[c * 32 + cc];
            val = s;
        } else if (c < 8) {
            int h = c - 4;
            float s = 0.f;
            #pragma unroll
            for (int cc = 0; cc < 32; ++cc) s += Wdr[(size_t)krow * 128 + h * 32 + cc] * adr[h * 32 + cc];
            val = s;
        } else {
            val = 0.f;
        }
        wf[f] = f2bf(val);
    }
    if (threadIdx.x < 128) {
        int p = threadIdx.x;
        bperm[bid * 128 + p] = bb[((p & 7) << 4) | (p >> 3)];
    }
}

// ---------------- shared gemm inner body ----------------
__device__ __forceinline__ void gemm_phases(const s16x8 af[2][4], u16* wlds,
        const u16* __restrict__ WfragL, int rel0, int nph,
        u16* __restrict__ Hs8, float* __restrict__ es8, float* __restrict__ ed8,
        int r0, int N, int tid) {
    const int l = tid & 63, lr = l & 15, lk = l >> 4;
    for (int ph = 0; ph < nph; ++ph) {
        const int r = rel0 + ph * 2;
        const u16* Wf = WfragL + (size_t)r * 18432;
        __syncthreads();
        for (int i = tid; i < 2304; i += 256)
            ((s16x8*)wlds)[i] = ((const s16x8*)Wf)[i];
        __syncthreads();

        f32x4 acc[2][9] = {};
        #pragma unroll
        for (int ct = 0; ct < 9; ++ct) {
            s16x8 bf0 = ((s16x8*)wlds)[(ct * 4 + 0) * 64 + l];
            s16x8 bf1 = ((s16x8*)wlds)[(ct * 4 + 1) * 64 + l];
            s16x8 bf2 = ((s16x8*)wlds)[(ct * 4 + 2) * 64 + l];
            s16x8 bf3 = ((s16x8*)wlds)[(ct * 4 + 3) * 64 + l];
            #pragma unroll
            for (int rt = 0; rt < 2; ++rt) {
                acc[rt][ct] = __builtin_amdgcn_mfma_f32_16x16x32_bf16(af[rt][0], bf0, acc[rt][ct], 0, 0, 0);
                acc[rt][ct] = __builtin_amdgcn_mfma_f32_16x16x32_bf16(af[rt][1], bf1, acc[rt][ct], 0, 0, 0);
                acc[rt][ct] = __builtin_amdgcn_mfma_f32_16x16x32_bf16(af[rt][2], bf2, acc[rt][ct], 0, 0, 0);
                acc[rt][ct] = __builtin_amdgcn_mfma_f32_16x16x32_bf16(af[rt][3], bf3, acc[rt][ct], 0, 0, 0);
            }
        }

        u16*   Hs = Hs8 + (size_t)r * N * 128;
        float* es = es8 + (size_t)r * N * 4;
        float* ed = ed8 + (size_t)(r ^ 1) * N * 4;
        #pragma unroll
        for (int rt = 0; rt < 2; ++rt) {
            #pragma unroll
            for (int j = 0; j < 4; ++j) {
                int row = r0 + rt * 16 + lk * 4 + j;
                if (row < N) {
                    union { u16 u[8]; uint4 q; } pk;
                    #pragma unroll
                    for (int ct = 0; ct < 8; ++ct) pk.u[ct] = f2bf(acc[rt][ct][j]);
                    *(uint4*)(Hs + (size_t)row * 128 + lr * 8) = pk.q;
                    float evv = acc[rt][8][j];
                    if (lr < 4)      es[(size_t)row * 4 + lr]     = evv;
                    else if (lr < 8) ed[(size_t)row * 4 + lr - 4] = evv;
                }
            }
        }
    }
}

__device__ __forceinline__ void ymap(int y, int& rel0, int& nph, int& stype) {
    if (y < 2) { rel0 = y * 4;           nph = 2; stype = 0; }
    else       { rel0 = 2 * (y - 2) + 1; nph = 1; stype = y - 1; }
}

// ---------------- fused: layer-1 gemm (fp32 in) INTERLEAVED with CSR build ----------
__global__ __launch_bounds__(256) void gemm1_build(
        const float* __restrict__ x0, const float* __restrict__ x1,
        const float* __restrict__ x2, const float* __restrict__ x3,
        const float* __restrict__ x4,
        const u16* __restrict__ WfragL,
        u16* __restrict__ Hs8, float* __restrict__ es8, float* __restrict__ ed8,
        const int* __restrict__ edges, int* __restrict__ pos, int* __restrict__ srcs,
        int gemmBlocks, int E, int N) {
    __shared__ u16 wlds[18432];
    const int bx = blockIdx.x;
    const int q = bx / 3, rm = bx % 3;
    const int tid = threadIdx.x;

    if (rm != 0) {
        const int bi = bx - q - 1;
        const int nEB = (E + 255) / 256;
        if (bi >= 8 * nEB) return;
        const int rel = bi & 7;
        const int e = (bi >> 3) * 256 + tid;
        if (e >= E) return;
        const int* b = edges + (size_t)rel * 2 * E;
        int s = b[e], d = b[E + e];
        int idx = atomicAdd(&pos[rel * N + d], 1);
        srcs[idx] = s;
        return;
    }
    if (q >= gemmBlocks * 6) return;
    const int gx = q % gemmBlocks;
    const int y  = q / gemmBlocks;
    int rel0, nph, stype;
    ymap(y, rel0, nph, stype);

    const int l = tid & 63, lr = l & 15, lk = l >> 4;
    const int wv = tid >> 6;
    const int r0 = gx * 128 + wv * 32;

    const float* Xf = stype == 0 ? x0 : stype == 1 ? x1 : stype == 2 ? x2
                    : stype == 3 ? x3 : x4;
    s16x8 af[2][4];
    #pragma unroll
    for (int rt = 0; rt < 2; ++rt) {
        int row = r0 + rt * 16 + lr;
        if (row > N - 1) row = N - 1;
        const float* xp = Xf + (size_t)row * 128 + lk * 8;
        #pragma unroll
        for (int qq = 0; qq < 4; ++qq) {
            float4 v0 = *(const float4*)(xp + qq * 32);
            float4 v1 = *(const float4*)(xp + qq * 32 + 4);
            s16x8 f;
            f[0] = (short)f2bf(v0.x); f[1] = (short)f2bf(v0.y);
            f[2] = (short)f2bf(v0.z); f[3] = (short)f2bf(v0.w);
            f[4] = (short)f2bf(v1.x); f[5] = (short)f2bf(v1.y);
            f[6] = (short)f2bf(v1.z); f[7] = (short)f2bf(v1.w);
            af[rt][qq] = f;
        }
    }
    gemm_phases(af, wlds, WfragL, rel0, nph, Hs8, es8, ed8, r0, N, tid);
}

// ---------------- layer-2 gemm (bf16 Xbf inputs), grid.y = 6 ----------------
__global__ __launch_bounds__(256) void gemm2_mfma(
        const u16* __restrict__ Xbf, const u16* __restrict__ WfragL,
        u16* __restrict__ Hs8, float* __restrict__ es8, float* __restrict__ ed8, int N) {
    __shared__ u16 wlds[18432];
    const int tid = threadIdx.x;
    int rel0, nph, stype;
    ymap(blockIdx.y, rel0, nph, stype);
    const int l = tid & 63, lr = l & 15, lk = l >> 4;
    const int wv = tid >> 6;
    const int r0 = blockIdx.x * 128 + wv * 32;

    const u16* X = Xbf + (size_t)stype * N * 128;
    s16x8 af[2][4];
    #pragma unroll
    for (int rt = 0; rt < 2; ++rt) {
        int row = r0 + rt * 16 + lr;
        if (row > N - 1) row = N - 1;
        const s16x8* xp = (const s16x8*)(X + (size_t)row * 128 + lk * 8);
        af[rt][0] = xp[0]; af[rt][1] = xp[4]; af[rt][2] = xp[8]; af[rt][3] = xp[12];
    }
    gemm_phases(af, wlds, WfragL, rel0, nph, Hs8, es8, ed8, r0, N, tid);
}

// ---------------- scan chain ----------------
__global__ __launch_bounds__(256) void scan_block_k(const int* __restrict__ in,
                                                    int* __restrict__ outv,
                                                    int* __restrict__ bsum, int M) {
    __shared__ int sh[256];
    int t = threadIdx.x;
    int base = blockIdx.x * 2048 + t * 8;
    int vals[8];
    int tot = 0;
    #pragma unroll
    for (int j = 0; j < 8; ++j) {
        int v = (base + j < M) ? in[base + j] : 0;
        vals[j] = tot; tot += v;
    }
    sh[t] = tot;
    __syncthreads();
    for (int ofs = 1; ofs < 256; ofs <<= 1) {
        int y = 0;
        if (t >= ofs) y = sh[t - ofs];
        __syncthreads();
        if (t >= ofs) sh[t] += y;
        __syncthreads();
    }
    int ex = (t == 0) ? 0 : sh[t - 1];
    #pragma unroll
    for (int j = 0; j < 8; ++j)
        if (base + j < M) outv[base + j] = ex + vals[j];
    if (t == 255) bsum[blockIdx.x] = sh[255];
}

__global__ __launch_bounds__(1024) void scan_tops_k(const int* __restrict__ bsum,
                                                    int* __restrict__ bpref, int nb) {
    __shared__ int sh[1024];
    int t = threadIdx.x;
    int v = (t < nb) ? bsum[t] : 0;
    sh[t] = v;
    __syncthreads();
    for (int ofs = 1; ofs < 1024; ofs <<= 1) {
        int y = 0;
        if (t >= ofs) y = sh[t - ofs];
        __syncthreads();
        if (t >= ofs) sh[t] += y;
        __syncthreads();
    }
    if (t < nb) bpref[t] = sh[t] - v;
}

__global__ void scan_add_k(int* __restrict__ outv, int* __restrict__ pos,
                           const int* __restrict__ bpref, int M) {
    int g = blockIdx.x * blockDim.x + threadIdx.x;
    if (g < M) {
        int v = outv[g] + bpref[g >> 11];
        outv[g] = v;
        pos[g] = v;
    }
}

// ---------------- pnorm (branchless first-4 for load ILP) ----------------
__global__ __launch_bounds__(256) void pnorm_k(
        const int* __restrict__ srcsG, const int* __restrict__ offs,
        const int* __restrict__ counts, const float* __restrict__ es8,
        const float* __restrict__ ed8, float* __restrict__ pcsr, int N) {
    const int r = blockIdx.y;
    const int* OFF = offs + (size_t)r * N;
    const int* CNT = counts + (size_t)r * N;
    const float* ES = es8 + (size_t)r * N * 4;
    const float* ED = ed8 + (size_t)r * N * 4;
    int g = blockIdx.x * 256 + threadIdx.x;
    if (g >= N * 4) return;
    const int d = g >> 2, h = g & 3;
    const int o0 = OFF[d], dg = CNT[d];
    if (dg == 0) return;
    const float edv = ED[(size_t)d * 4 + h];
    float lc[8];
    float mx = -INFINITY;
    #pragma unroll
    for (int i = 0; i < 4; ++i) {
        int idx = o0 + (i < dg ? i : 0);
        int s = srcsG[idx];
        float lv = ES[(size_t)s * 4 + h] + edv;
        lv = lv > 0.f ? lv : 0.2f * lv;
        if (i >= dg) lv = -INFINITY;
        lc[i] = lv;
        mx = fmaxf(mx, lv);
    }
    #pragma unroll
    for (int i = 4; i < 8; ++i) {
        float lv = -INFINITY;
        if (i < dg) {
            int s = srcsG[o0 + i];
            lv = ES[(size_t)s * 4 + h] + edv;
            lv = lv > 0.f ? lv : 0.2f * lv;
            mx = fmaxf(mx, lv);
        }
        lc[i] = lv;
    }
    for (int i = 8; i < dg; ++i) {
        int s = srcsG[o0 + i];
        float lv = ES[(size_t)s * 4 + h] + edv;
        lv = lv > 0.f ? lv : 0.2f * lv;
        mx = fmaxf(mx, lv);
    }
    float den = 0.f;
    #pragma unroll
    for (int i = 0; i < 8; ++i) {
        lc[i] = __expf(lc[i] - mx);
        den += lc[i];
    }
    for (int i = 8; i < dg; ++i) {
        int s = srcsG[o0 + i];
        float lv = ES[(size_t)s * 4 + h] + edv;
        lv = lv > 0.f ? lv : 0.2f * lv;
        den += __expf(lv - mx);
    }
    const float inv = 1.f / (den + 1e-16f);
    #pragma unroll
    for (int i = 0; i < 8; ++i) {
        if (i < dg) pcsr[(size_t)(o0 + i) * 4 + h] = lc[i] * inv;
    }
    for (int i = 8; i < dg; ++i) {
        int s = srcsG[o0 + i];
        float lv = ES[(size_t)s * 4 + h] + edv;
        lv = lv > 0.f ? lv : 0.2f * lv;
        pcsr[(size_t)(o0 + i) * 4 + h] = __expf(lv - mx) * inv;
    }
}

// ---------------- gather accumulate for one relation (round-13 form) ----------------
__device__ __forceinline__ void acc_rel(float a[8], const int* __restrict__ srcsG,
        const float* __restrict__ pcsr, const int* __restrict__ OFF,
        const int* __restrict__ CNT, const u16* __restrict__ HS,
        int ds, bool act, int ln) {
    const int o0 = OFF[ds];
    const int dg = act ? CNT[ds] : 0;
    if (dg == 0) return;
    #pragma unroll
    for (int i = 0; i < 4; ++i) {
        int idx = o0 + (i < dg ? i : dg - 1);
        int s = srcsG[idx];
        float4 p4 = *(const float4*)(pcsr + (size_t)idx * 4);
        uint4 hv  = *(const uint4*)(HS + (size_t)s * 128 + 8 * ln);
        if (i >= dg) { p4.x = 0.f; p4.y = 0.f; p4.z = 0.f; p4.w = 0.f; }
        a[0] += p4.x * bf2f((u16)(hv.x & 0xFFFF)); a[1] += p4.x * bf2f((u16)(hv.x >> 16));
        a[2] += p4.y * bf2f((u16)(hv.y & 0xFFFF)); a[3] += p4.y * bf2f((u16)(hv.y >> 16));
        a[4] += p4.z * bf2f((u16)(hv.z & 0xFFFF)); a[5] += p4.z * bf2f((u16)(hv.z >> 16));
        a[6] += p4.w * bf2f((u16)(hv.w & 0xFFFF)); a[7] += p4.w * bf2f((u16)(hv.w >> 16));
    }
    #pragma unroll
    for (int i = 4; i < 8; ++i) {
        if (i < dg) {
            int idx = o0 + i;
            int s = srcsG[idx];
            float4 p4 = *(const float4*)(pcsr + (size_t)idx * 4);
            uint4 hv  = *(const uint4*)(HS + (size_t)s * 128 + 8 * ln);
            a[0] += p4.x * bf2f((u16)(hv.x & 0xFFFF)); a[1] += p4.x * bf2f((u16)(hv.x >> 16));
            a[2] += p4.y * bf2f((u16)(hv.y & 0xFFFF)); a[3] += p4.y * bf2f((u16)(hv.y >> 16));
            a[4] += p4.z * bf2f((u16)(hv.z & 0xFFFF)); a[5] += p4.z * bf2f((u16)(hv.z >> 16));
            a[6] += p4.w * bf2f((u16)(hv.w & 0xFFFF)); a[7] += p4.w * bf2f((u16)(hv.w >> 16));
        }
    }
    for (int i = 8; i < dg; ++i) {
        int idx = o0 + i;
        int s = srcsG[idx];
        float4 p4 = *(const float4*)(pcsr + (size_t)idx * 4);
        uint4 hv  = *(const uint4*)(HS + (size_t)s * 128 + 8 * ln);
        a[0] += p4.x * bf2f((u16)(hv.x & 0xFFFF)); a[1] += p4.x * bf2f((u16)(hv.x >> 16));
        a[2] += p4.y * bf2f((u16)(hv.y & 0xFFFF)); a[3] += p4.y * bf2f((u16)(hv.y >> 16));
        a[4] += p4.z * bf2f((u16)(hv.z & 0xFFFF)); a[5] += p4.z * bf2f((u16)(hv.z >> 16));
        a[6] += p4.w * bf2f((u16)(hv.w & 0xFFFF)); a[7] += p4.w * bf2f((u16)(hv.w >> 16));
    }
}

// ---------------- merged gather (round-13 form): y=0 -> type 0; y=1..4 -> type y ----
// OUT_MODE 0: ELU->bf16 perm layout (Xbf). OUT_MODE 2: ELU fp32 un-permuted (d_out).
template<int OUT_MODE>
__global__ __launch_bounds__(256) void gat_all(
        const int* __restrict__ srcsG, const float* __restrict__ pcsr,
        const int* __restrict__ offs, const int* __restrict__ counts,
        const u16* __restrict__ Hs8, const float* __restrict__ bpermL,
        const float* __restrict__ b0sumL, void* __restrict__ outBase, int N) {
    const int y   = blockIdx.y;
    const int tid = threadIdx.x;
    const int ln  = tid & 15;
    const int d   = (blockIdx.x * 256 + tid) >> 4;
    const bool act = (d < N);
    const int ds = act ? d : 0;

    float a[8] = {};
    const float* bb;
    size_t slice;
    if (y == 0) {
        #pragma unroll
        for (int rr = 0; rr < 4; ++rr) {
            const int rel = 2 * rr + 1;
            acc_rel(a, srcsG, pcsr, offs + (size_t)rel * N, counts + (size_t)rel * N,
                    Hs8 + (size_t)rel * N * 128, ds, act, ln);
        }
        bb = b0sumL;
        slice = 0;
    } else {
        const int rel = 2 * (y - 1);
        acc_rel(a, srcsG, pcsr, offs + (size_t)rel * N, counts + (size_t)rel * N,
                Hs8 + (size_t)rel * N * 128, ds, act, ln);
        bb = bpermL + (size_t)rel * 128;
        slice = (size_t)y * N * 128;
    }
    if (!act) return;

    float4 b0 = *(const float4*)(bb + 8 * ln);
    float4 b1 = *(const float4*)(bb + 8 * ln + 4);
    a[0] += b0.x; a[1] += b0.y; a[2] += b0.z; a[3] += b0.w;
    a[4] += b1.x; a[5] += b1.y; a[6] += b1.z; a[7] += b1.w;

    if (OUT_MODE == 0) {
        u16* OP = (u16*)outBase + slice;
        union { u16 u[8]; uint4 q; } pk;
        #pragma unroll
        for (int j = 0; j < 8; ++j) pk.u[j] = f2bf(eluf(a[j]));
        *(uint4*)(OP + (size_t)d * 128 + 8 * ln) = pk.q;
    } else {
        float* OP = (float*)outBase + slice;
        float* o = OP + (size_t)d * 128;
        #pragma unroll
        for (int j = 0; j < 8; ++j)
            o[(j << 4) | ln] = eluf(a[j]);
    }
}

extern "C" void kernel_launch(void* const* d_in, const int* in_sizes, int n_in,
                              void* d_out, int out_size, void* d_ws, size_t ws_size,
                              hipStream_t stream) {
    const int N = in_sizes[0] / 128;
    const int E = in_sizes[5] / (2 * NRELS);

    const float* xs0[5] = { (const float*)d_in[0], (const float*)d_in[1],
                            (const float*)d_in[2], (const float*)d_in[3],
                            (const float*)d_in[4] };
    const int*   edges = (const int*)d_in[5];
    const float* Ws1 = (const float*)d_in[6];
    const float* Wd1 = (const float*)d_in[7];
    const float* as1 = (const float*)d_in[8];
    const float* ad1 = (const float*)d_in[9];
    const float* b1  = (const float*)d_in[10];
    const float* Ws2 = (const float*)d_in[11];
    const float* Wd2 = (const float*)d_in[12];
    const float* as2 = (const float*)d_in[13];
    const float* ad2 = (const float*)d_in[14];
    const float* b2  = (const float*)d_in[15];
    float* out = (float*)d_out;

    // workspace layout (~417 MB; ws_size ~1 GB)
    char* wp = (char*)d_ws;
    u16*   Xbf   = (u16*)wp;   wp += (size_t)5 * N * 128 * 2;
    u16*   Hs8   = (u16*)wp;   wp += (size_t)8 * N * 128 * 2;
    float* es8   = (float*)wp; wp += (size_t)8 * N * 4 * 4;
    float* ed8   = (float*)wp; wp += (size_t)8 * N * 4 * 4;
    float* pcsr  = (float*)wp; wp += (size_t)NRELS * E * 4 * 4;
    int* counts  = (int*)wp;   wp += (size_t)NRELS * N * 4;
    int* offs    = (int*)wp;   wp += (size_t)NRELS * N * 4;
    int* pos     = (int*)wp;   wp += (size_t)NRELS * N * 4;
    int* srcs    = (int*)wp;   wp += (size_t)NRELS * E * 4;
    u16* Wfrag   = (u16*)wp;   wp += (size_t)16 * 18432 * 2;
    float* bperm = (float*)wp; wp += (size_t)16 * 128 * 4;
    float* b0sum = (float*)wp; wp += (size_t)2 * 128 * 4;
    int* bsum    = (int*)wp;   wp += 1024 * 4;
    int* bpref   = (int*)wp;   wp += 1024 * 4;
    const size_t ws_used = (size_t)(wp - (char*)d_ws);
    if (ws_used > ws_size) return;

    // ---- zero ONLY the atomic histogram (write-before-read audit holds elsewhere) --
    const int M = NRELS * N;
    hipMemsetAsync(counts, 0, (size_t)M * 4, stream);

    const int nEB = (E + 255) / 256;
    const int eblocks = 8 * nEB;

    prep_hist<<<dim3(18 + eblocks), 256, 0, stream>>>(
        Ws1, Wd1, as1, ad1, b1, Ws2, Wd2, as2, ad2, b2,
        Wfrag, bperm, b0sum, edges, counts, E, N);

    const int nb = (M + 2047) / 2048;
    scan_block_k<<<dim3(nb), 256, 0, stream>>>(counts, offs, bsum, M);
    scan_tops_k<<<dim3(1), 1024, 0, stream>>>(bsum, bpref, nb);
    scan_add_k<<<dim3((M + 255) / 256), 256, 0, stream>>>(offs, pos, bpref, M);

    const int gemmBlocks  = (N + 127) / 128;
    const int G6          = gemmBlocks * 6;
    const int gBlocks     = (N + 15) / 16;
    const int pnormBlocks = (N * 4 + 255) / 256;

    const int K = (G6 > (eblocks + 1) / 2) ? G6 : (eblocks + 1) / 2;

    for (int layer = 0; layer < 2; ++layer) {
        const u16*   WL = Wfrag + (size_t)layer * 8 * 18432;
        const float* bL = bperm + layer * 8 * 128;

        if (layer == 0) {
            gemm1_build<<<dim3(3 * K), 256, 0, stream>>>(
                xs0[0], xs0[1], xs0[2], xs0[3], xs0[4],
                WL, Hs8, es8, ed8, edges, pos, srcs, gemmBlocks, E, N);
        } else {
            gemm2_mfma<<<dim3(gemmBlocks, 6), 256, 0, stream>>>(
                Xbf, WL, Hs8, es8, ed8, N);
        }

        pnorm_k<<<dim3(pnormBlocks, 8), 256, 0, stream>>>(
            srcs, offs, counts, es8, ed8, pcsr, N);

        if (layer == 0)
            gat_all<0><<<dim3(gBlocks, 5), 256, 0, stream>>>(
                srcs, pcsr, offs, counts, Hs8, bL, b0sum + 0 * 128, Xbf, N);
        else
            gat_all<2><<<dim3(gBlocks, 5), 256, 0, stream>>>(
                srcs, pcsr, offs, counts, Hs8, bL, b0sum + 1 * 128, out, N);
    }
}